// Round 1
// baseline (732.375 us; speedup 1.0000x reference)
//
#include <hip/hip_runtime.h>
#include <hip/hip_bf16.h>
#include <math.h>

typedef __bf16 bf16;
typedef __bf16 bf16x8 __attribute__((ext_vector_type(8)));
typedef float  f32x4  __attribute__((ext_vector_type(4)));

#define NB    2
#define NT    2048
#define NH    16
#define ND    64
#define NC    1024
#define NBT   4096   /* NB*NT */

#define AS1C(p) ((const __attribute__((address_space(1))) void*)(p))
#define AS3(p)  ((__attribute__((address_space(3))) void*)(p))

// ---------------- fp32 -> bf16 cast ----------------
__global__ void cast_kernel(const float* __restrict__ src, bf16* __restrict__ dst, int n)
{
    int i = (blockIdx.x * blockDim.x + threadIdx.x) * 4;
    if (i + 3 < n) {
        float4 v = *reinterpret_cast<const float4*>(src + i);
        dst[i+0] = (bf16)v.x;
        dst[i+1] = (bf16)v.y;
        dst[i+2] = (bf16)v.z;
        dst[i+3] = (bf16)v.w;
    }
}

// ---------------- GEMM  C = A(MxK) * B(NxK)^T ----------------
// EPI=0: proj epilogue -> bf16 QKV [p][b][h][t][d] with RoPE on p<4
// EPI=1: plain fp32 row-major output (stride N)
template<int EPI>
__global__ __launch_bounds__(256)
void gemm_bt(const bf16* __restrict__ A, const bf16* __restrict__ Bw,
             void* __restrict__ Cout, int M, int N, int K)
{
    __shared__ bf16 As[128*64];
    __shared__ bf16 Bs[128*64];

    const int tid  = threadIdx.x;
    const int lane = tid & 63;
    const int w    = tid >> 6;       // wave 0..3
    const int wr   = w >> 1;         // 2x2 wave grid
    const int wc   = w & 1;
    const int row0 = blockIdx.y * 128;
    const int col0 = blockIdx.x * 128;

    const int lo   = lane & 15;
    const int hi8  = (lane >> 4) * 8;
    const int srow = w * 8 + (lane >> 3);  // staging row within a 32-row pass
    const int scol = (lane & 7) * 8;       // staging col (elements)

    f32x4 acc[4][4] = {};

    for (int kt = 0; kt < K; kt += 64) {
        #pragma unroll
        for (int i = 0; i < 4; ++i) {
            const unsigned loff = (unsigned)(i * 4096 + w * 1024); // + lane*16 by HW
            __builtin_amdgcn_global_load_lds(
                AS1C(A + (size_t)(row0 + i*32 + srow) * K + kt + scol),
                AS3((char*)As + loff), 16, 0, 0);
            __builtin_amdgcn_global_load_lds(
                AS1C(Bw + (size_t)(col0 + i*32 + srow) * K + kt + scol),
                AS3((char*)Bs + loff), 16, 0, 0);
        }
        __syncthreads();
        #pragma unroll
        for (int ks = 0; ks < 2; ++ks) {
            bf16x8 af[4], bfr[4];
            #pragma unroll
            for (int m = 0; m < 4; ++m)
                af[m] = *reinterpret_cast<const bf16x8*>(&As[(wr*64 + m*16 + lo)*64 + ks*32 + hi8]);
            #pragma unroll
            for (int n = 0; n < 4; ++n)
                bfr[n] = *reinterpret_cast<const bf16x8*>(&Bs[(wc*64 + n*16 + lo)*64 + ks*32 + hi8]);
            #pragma unroll
            for (int m = 0; m < 4; ++m)
                #pragma unroll
                for (int n = 0; n < 4; ++n)
                    acc[m][n] = __builtin_amdgcn_mfma_f32_16x16x32_bf16(af[m], bfr[n], acc[m][n], 0, 0, 0);
        }
        __syncthreads();
    }

    const int rb = (lane >> 4) * 4;
    if constexpr (EPI == 1) {
        float* Cp = (float*)Cout;
        #pragma unroll
        for (int m = 0; m < 4; ++m)
            #pragma unroll
            for (int n = 0; n < 4; ++n)
                #pragma unroll
                for (int r = 0; r < 4; ++r) {
                    int row = row0 + wr*64 + m*16 + rb + r;
                    int col = col0 + wc*64 + n*16 + lo;
                    Cp[(size_t)row * N + col] = acc[m][n][r];
                }
    } else {
        bf16* qkv = (bf16*)Cout;
        const int colh = col0 + wc*64;       // multiple of 64 -> exactly one head
        const int p = colh >> 10;            // which projection (q1,k1,q2,k2,v)
        const int h = (colh >> 6) & (NH-1);
        const bool rope = (p < 4);
        #pragma unroll
        for (int m = 0; m < 4; ++m) {
            #pragma unroll
            for (int r = 0; r < 4; ++r) {
                const int rowg = row0 + wr*64 + m*16 + rb + r;
                const int b = rowg >> 11;        // / NT
                const int t = rowg & (NT-1);
                bf16* dst = qkv + ((((size_t)p*NB + b)*NH + h)*NT + t)*ND;
                if (rope) {
                    #pragma unroll
                    for (int n = 0; n < 2; ++n) {
                        const int j = n*16 + lo;                 // 0..31
                        float invf = 1.0f / powf(10000.0f, (float)j * (1.0f/32.0f));
                        float fr = (float)t * invf;
                        float c = (float)(bf16)cosf(fr);         // match reference bf16 round
                        float s = (float)(bf16)sinf(fr);
                        float a1 = acc[m][n][r];     // d = j
                        float a2 = acc[m][n+2][r];   // d = j+32
                        dst[j]    = (bf16)(a1*c + a2*s);
                        dst[j+32] = (bf16)(a2*c - a1*s);
                    }
                } else {
                    #pragma unroll
                    for (int n = 0; n < 4; ++n)
                        dst[n*16 + lo] = (bf16)acc[m][n][r];
                }
            }
        }
    }
}

// ---------------- fused bilinear attention ----------------
// grid (T/64, H, B), 256 threads = 4 waves, each wave owns 16 q-rows
__global__ __launch_bounds__(256)
void attn_kernel(const bf16* __restrict__ qkv, bf16* __restrict__ Y)
{
    __shared__ bf16 K1s[64*64];
    __shared__ bf16 K2s[64*64];
    __shared__ bf16 Vt [64*72];      // transposed V, padded (+8) for bank spread
    __shared__ bf16 Pl [4][16*72];   // per-wave P staging, padded

    const int tid  = threadIdx.x;
    const int lane = tid & 63;
    const int w    = tid >> 6;
    const int qt = blockIdx.x, h = blockIdx.y, b = blockIdx.z;
    const int q0 = qt * 64;

    const size_t plane = (size_t)NB * NH * NT * ND;
    const size_t bh    = ((size_t)b * NH + h) * NT * ND;
    const bf16* Q1 = qkv + 0*plane + bh;
    const bf16* K1 = qkv + 1*plane + bh;
    const bf16* Q2 = qkv + 2*plane + bh;
    const bf16* K2 = qkv + 3*plane + bh;
    const bf16* V  = qkv + 4*plane + bh;

    const int lo  = lane & 15;
    const int hi  = lane >> 4;
    const int hi8 = hi * 8;

    // Q fragments (A-operand, row = lane%16) for this wave's 16 rows, K-dim = D = 64
    bf16x8 q1f[2], q2f[2];
    #pragma unroll
    for (int ks = 0; ks < 2; ++ks) {
        q1f[ks] = *reinterpret_cast<const bf16x8*>(Q1 + (size_t)(q0 + w*16 + lo)*ND + ks*32 + hi8);
        q2f[ks] = *reinterpret_cast<const bf16x8*>(Q2 + (size_t)(q0 + w*16 + lo)*ND + ks*32 + hi8);
    }

    f32x4 yacc[4] = {};

    const int srow = w * 8 + (lane >> 3);
    const int scol = (lane & 7) * 8;
    const int rot  = (tid >> 3) & 7;      // rotation to break Vt write bank conflicts

    const int nkt = qt + 1;
    for (int kt = 0; kt < nkt; ++kt) {
        const int k0 = kt * 64;
        // --- stage K1, K2 (linear LDS via global_load_lds) ---
        #pragma unroll
        for (int i = 0; i < 2; ++i) {
            const unsigned loff = (unsigned)(i * 4096 + w * 1024);
            __builtin_amdgcn_global_load_lds(
                AS1C(K1 + (size_t)(k0 + i*32 + srow) * ND + scol),
                AS3((char*)K1s + loff), 16, 0, 0);
            __builtin_amdgcn_global_load_lds(
                AS1C(K2 + (size_t)(k0 + i*32 + srow) * ND + scol),
                AS3((char*)K2s + loff), 16, 0, 0);
        }
        // --- stage V transposed (reg -> LDS) ---
        #pragma unroll
        for (int i = 0; i < 2; ++i) {
            const int t  = i*32 + (tid >> 3);
            const int d0 = (tid & 7) * 8;
            bf16x8 vv = *reinterpret_cast<const bf16x8*>(V + (size_t)(k0 + t) * ND + d0);
            #pragma unroll
            for (int j = 0; j < 8; ++j) {
                const int jj = (j + rot) & 7;
                Vt[(d0 + jj)*72 + t] = vv[jj];
            }
        }
        __syncthreads();

        // --- S1 = Q1*K1^T, S2 = Q2*K2^T (16 q-rows x 64 k-cols per wave) ---
        f32x4 s1[4] = {}, s2[4] = {};
        #pragma unroll
        for (int ks = 0; ks < 2; ++ks)
            #pragma unroll
            for (int sub = 0; sub < 4; ++sub) {
                bf16x8 k1f = *reinterpret_cast<const bf16x8*>(&K1s[(sub*16 + lo)*64 + ks*32 + hi8]);
                bf16x8 k2f = *reinterpret_cast<const bf16x8*>(&K2s[(sub*16 + lo)*64 + ks*32 + hi8]);
                s1[sub] = __builtin_amdgcn_mfma_f32_16x16x32_bf16(q1f[ks], k1f, s1[sub], 0, 0, 0);
                s2[sub] = __builtin_amdgcn_mfma_f32_16x16x32_bf16(q2f[ks], k2f, s2[sub], 0, 0, 0);
            }

        // --- combine + causal mask -> P (bf16) via per-wave LDS ---
        #pragma unroll
        for (int sub = 0; sub < 4; ++sub)
            #pragma unroll
            for (int r = 0; r < 4; ++r) {
                const int qg = q0 + w*16 + hi*4 + r;
                const int kg = k0 + sub*16 + lo;
                float pv = (kg <= qg) ? s1[sub][r] * s2[sub][r] * (1.0f/4096.0f) : 0.0f;
                Pl[w][(hi*4 + r)*72 + sub*16 + lo] = (bf16)pv;
            }
        asm volatile("s_waitcnt lgkmcnt(0)" ::: "memory");
        __builtin_amdgcn_sched_barrier(0);

        // --- Y += P * V ---
        #pragma unroll
        for (int ks = 0; ks < 2; ++ks) {
            bf16x8 pf = *reinterpret_cast<const bf16x8*>(&Pl[w][lo*72 + ks*32 + hi8]);
            #pragma unroll
            for (int n = 0; n < 4; ++n) {
                bf16x8 vf = *reinterpret_cast<const bf16x8*>(&Vt[(n*16 + lo)*72 + ks*32 + hi8]);
                yacc[n] = __builtin_amdgcn_mfma_f32_16x16x32_bf16(pf, vf, yacc[n], 0, 0, 0);
            }
        }
        __syncthreads();   // protect K1s/K2s/Vt before next stage
    }

    // --- write Y [b][t][c] bf16 ---
    #pragma unroll
    for (int n = 0; n < 4; ++n)
        #pragma unroll
        for (int r = 0; r < 4; ++r) {
            const int t = q0 + w*16 + hi*4 + r;
            const int c = h*ND + n*16 + lo;
            Y[((size_t)b*NT + t)*NC + c] = (bf16)yacc[n][r];
        }
}

// ---------------- launch ----------------
extern "C" void kernel_launch(void* const* d_in, const int* in_sizes, int n_in,
                              void* d_out, int out_size, void* d_ws, size_t ws_size,
                              hipStream_t stream)
{
    const float* x    = (const float*)d_in[0];
    const float* Wq1  = (const float*)d_in[1];
    const float* Wk1  = (const float*)d_in[2];
    const float* Wq2  = (const float*)d_in[3];
    const float* Wk2  = (const float*)d_in[4];
    const float* Wv   = (const float*)d_in[5];
    const float* Wout = (const float*)d_in[6];

    char* ws = (char*)d_ws;
    bf16* Xbf   = (bf16*)ws;                                              // 8 MB
    bf16* Wcat  = (bf16*)(ws + (size_t)NBT*NC*2);                         // 10 MB
    bf16* Woutb = (bf16*)(ws + (size_t)NBT*NC*2 + (size_t)5*NC*NC*2);     // 2 MB
    bf16* QKV   = (bf16*)(ws + (size_t)NBT*NC*2 + (size_t)6*NC*NC*2);     // 40 MB
    bf16* Ybf   = (bf16*)((char*)QKV + (size_t)5*NBT*NC*2);               // 8 MB

    cast_kernel<<<dim3(NBT*NC/1024), 256, 0, stream>>>(x, Xbf, NBT*NC);
    const float* Ws[5] = {Wq1, Wk1, Wq2, Wk2, Wv};
    for (int p = 0; p < 5; ++p)
        cast_kernel<<<dim3(NC*NC/1024), 256, 0, stream>>>(Ws[p], Wcat + (size_t)p*NC*NC, NC*NC);
    cast_kernel<<<dim3(NC*NC/1024), 256, 0, stream>>>(Wout, Woutb, NC*NC);

    // fused 5-projection GEMM, RoPE in epilogue -> QKV [p][b][h][t][d]
    gemm_bt<0><<<dim3(5*NC/128, NBT/128), 256, 0, stream>>>(Xbf, Wcat, (void*)QKV, NBT, 5*NC, NC);
    // fused bilinear attention -> Ybf [b][t][c]
    attn_kernel<<<dim3(NT/64, NH, NB), 256, 0, stream>>>(QKV, Ybf);
    // output projection -> fp32 d_out
    gemm_bt<1><<<dim3(NC/128, NBT/128), 256, 0, stream>>>(Ybf, Woutb, d_out, NBT, NC, NC);
}

// Round 2
// 301.047 us; speedup vs baseline: 2.4328x; 2.4328x over previous
//
#include <hip/hip_runtime.h>
#include <hip/hip_bf16.h>
#include <math.h>

typedef __bf16 bf16;
typedef __bf16 bf16x8 __attribute__((ext_vector_type(8)));
typedef float  f32x4  __attribute__((ext_vector_type(4)));

#define NB    2
#define NT    2048
#define NH    16
#define ND    64
#define NC    1024
#define NBT   4096   /* NB*NT */

#define AS1C(p) ((const __attribute__((address_space(1))) void*)(p))
#define AS3(p)  ((__attribute__((address_space(3))) void*)(p))

// ---------------- fp32 -> bf16 cast ----------------
__global__ void cast_kernel(const float* __restrict__ src, bf16* __restrict__ dst, int n)
{
    int i = (blockIdx.x * blockDim.x + threadIdx.x) * 4;
    if (i + 3 < n) {
        float4 v = *reinterpret_cast<const float4*>(src + i);
        dst[i+0] = (bf16)v.x;
        dst[i+1] = (bf16)v.y;
        dst[i+2] = (bf16)v.z;
        dst[i+3] = (bf16)v.w;
    }
}

// ---------------- rope cos/sin table (bf16-rounded, fp32 storage) ----------------
// tbl[t*32 + j] = (cos, sin) of t / 10000^(j/32)
__global__ void rope_table_kernel(float2* __restrict__ tbl)
{
    int i = blockIdx.x * 256 + threadIdx.x;   // 0 .. NT*32-1
    int t = i >> 5, j = i & 31;
    float invf = 1.0f / powf(10000.0f, (float)j * (1.0f/32.0f));
    float fr = (float)t * invf;
    float2 cs;
    cs.x = (float)(bf16)cosf(fr);
    cs.y = (float)(bf16)sinf(fr);
    tbl[i] = cs;
}

// ---------------- GEMM  C = A(MxK) * B(NxK)^T ----------------
// EPI=0: proj epilogue -> bf16 QKV [p][b][h][t][d] with RoPE on p<4 (table-driven,
//        LDS-staged, coalesced 16B stores)
// EPI=1: plain fp32 row-major output (stride N), dword stores
template<int EPI>
__global__ __launch_bounds__(256)
void gemm_bt(const bf16* __restrict__ A, const bf16* __restrict__ Bw,
             void* __restrict__ Cout, int M, int N, int K,
             const float2* __restrict__ tbl)
{
    __shared__ bf16 smem[128*128];          // 32 KB: As(16KB)+Bs(16KB), reused as C-tile
    bf16* As = smem;
    bf16* Bs = smem + 128*64;

    const int tid  = threadIdx.x;
    const int lane = tid & 63;
    const int w    = tid >> 6;       // wave 0..3
    const int wr   = w >> 1;         // 2x2 wave grid
    const int wc   = w & 1;
    const int row0 = blockIdx.y * 128;
    const int col0 = blockIdx.x * 128;

    const int lo   = lane & 15;
    const int hi8  = (lane >> 4) * 8;
    const int srow = w * 8 + (lane >> 3);  // staging row within a 32-row pass
    const int scol = (lane & 7) * 8;       // staging col (elements)

    f32x4 acc[4][4] = {};

    for (int kt = 0; kt < K; kt += 64) {
        #pragma unroll
        for (int i = 0; i < 4; ++i) {
            const unsigned loff = (unsigned)(i * 4096 + w * 1024); // + lane*16 by HW
            __builtin_amdgcn_global_load_lds(
                AS1C(A + (size_t)(row0 + i*32 + srow) * K + kt + scol),
                AS3((char*)As + loff), 16, 0, 0);
            __builtin_amdgcn_global_load_lds(
                AS1C(Bw + (size_t)(col0 + i*32 + srow) * K + kt + scol),
                AS3((char*)Bs + loff), 16, 0, 0);
        }
        __syncthreads();
        #pragma unroll
        for (int ks = 0; ks < 2; ++ks) {
            bf16x8 af[4], bfr[4];
            #pragma unroll
            for (int m = 0; m < 4; ++m)
                af[m] = *reinterpret_cast<const bf16x8*>(&As[(wr*64 + m*16 + lo)*64 + ks*32 + hi8]);
            #pragma unroll
            for (int n = 0; n < 4; ++n)
                bfr[n] = *reinterpret_cast<const bf16x8*>(&Bs[(wc*64 + n*16 + lo)*64 + ks*32 + hi8]);
            #pragma unroll
            for (int m = 0; m < 4; ++m)
                #pragma unroll
                for (int n = 0; n < 4; ++n)
                    acc[m][n] = __builtin_amdgcn_mfma_f32_16x16x32_bf16(af[m], bfr[n], acc[m][n], 0, 0, 0);
        }
        __syncthreads();
    }

    const int rb = (lane >> 4) * 4;
    if constexpr (EPI == 1) {
        float* Cp = (float*)Cout;
        #pragma unroll
        for (int m = 0; m < 4; ++m)
            #pragma unroll
            for (int n = 0; n < 4; ++n)
                #pragma unroll
                for (int r = 0; r < 4; ++r) {
                    int row = row0 + wr*64 + m*16 + rb + r;
                    int col = col0 + wc*64 + n*16 + lo;
                    Cp[(size_t)row * N + col] = acc[m][n][r];
                }
    } else {
        // ---- stage C tile (bf16, rope applied) into LDS with XOR swizzle ----
        // byte addr within tile = row*256 + (col*2 ^ key(row)), key = ((row>>2)&3)<<5
        bf16* Ct = smem;
        const bool rope = (col0 >> 10) < 4;
        if (rope) {
            #pragma unroll
            for (int m = 0; m < 4; ++m)
                #pragma unroll
                for (int r = 0; r < 4; ++r) {
                    const int rl = wr*64 + m*16 + rb + r;
                    const int t  = (row0 + rl) & (NT-1);
                    const unsigned key = ((unsigned)(rl >> 2) & 3) << 5;
                    #pragma unroll
                    for (int n = 0; n < 2; ++n) {
                        const int j = n*16 + lo;
                        float2 cs = tbl[t*32 + j];
                        float a1 = acc[m][n][r];     // d = j
                        float a2 = acc[m][n+2][r];   // d = j+32
                        const int c1 = wc*64 + j;
                        const int c2 = c1 + 32;
                        Ct[((unsigned)rl*256 + (((unsigned)c1*2) ^ key)) >> 1] = (bf16)(a1*cs.x + a2*cs.y);
                        Ct[((unsigned)rl*256 + (((unsigned)c2*2) ^ key)) >> 1] = (bf16)(a2*cs.x - a1*cs.y);
                    }
                }
        } else {
            #pragma unroll
            for (int m = 0; m < 4; ++m)
                #pragma unroll
                for (int r = 0; r < 4; ++r) {
                    const int rl = wr*64 + m*16 + rb + r;
                    const unsigned key = ((unsigned)(rl >> 2) & 3) << 5;
                    #pragma unroll
                    for (int n = 0; n < 4; ++n) {
                        const int c = wc*64 + n*16 + lo;
                        Ct[((unsigned)rl*256 + (((unsigned)c*2) ^ key)) >> 1] = (bf16)acc[m][n][r];
                    }
                }
        }
        __syncthreads();

        // ---- coalesced writeout: 128 rows x 16 chunks of 16B ----
        bf16* qkv = (bf16*)Cout;
        const int p  = col0 >> 10;
        const int h0 = (col0 >> 6) & (NH-1);
        #pragma unroll
        for (int it = 0; it < 8; ++it) {
            const int chunk = it*256 + tid;       // 0..2047
            const int rl = chunk >> 4;            // local row
            const int cc = chunk & 15;            // 16B chunk in row
            const unsigned key = ((unsigned)(rl >> 2) & 3) << 5;
            bf16x8 val = *reinterpret_cast<const bf16x8*>(
                (const char*)Ct + ((unsigned)rl*256 + (((unsigned)cc*16) ^ key)));
            const int rowg = row0 + rl;
            const int b = rowg >> 11;
            const int t = rowg & (NT-1);
            const int hh = h0 + (cc >> 3);
            const int d  = (cc & 7) * 8;
            *reinterpret_cast<bf16x8*>(
                qkv + ((((size_t)p*NB + b)*NH + hh)*NT + t)*ND + d) = val;
        }
    }
}

// ---------------- fused bilinear attention ----------------
// grid (T/64, H, B), 256 threads = 4 waves, each wave owns 16 q-rows
__global__ __launch_bounds__(256)
void attn_kernel(const bf16* __restrict__ qkv, bf16* __restrict__ Y)
{
    __shared__ bf16 K1s[64*64];
    __shared__ bf16 K2s[64*64];
    __shared__ bf16 Vt [64*72];      // transposed V, padded (+8) for bank spread
    __shared__ bf16 Pl [4][16*72];   // per-wave P staging, padded

    const int tid  = threadIdx.x;
    const int lane = tid & 63;
    const int w    = tid >> 6;
    const int qt = blockIdx.x, h = blockIdx.y, b = blockIdx.z;
    const int q0 = qt * 64;

    const size_t plane = (size_t)NB * NH * NT * ND;
    const size_t bh    = ((size_t)b * NH + h) * NT * ND;
    const bf16* Q1 = qkv + 0*plane + bh;
    const bf16* K1 = qkv + 1*plane + bh;
    const bf16* Q2 = qkv + 2*plane + bh;
    const bf16* K2 = qkv + 3*plane + bh;
    const bf16* V  = qkv + 4*plane + bh;

    const int lo  = lane & 15;
    const int hi  = lane >> 4;
    const int hi8 = hi * 8;

    // Q fragments (A-operand, row = lane%16) for this wave's 16 rows, K-dim = D = 64
    bf16x8 q1f[2], q2f[2];
    #pragma unroll
    for (int ks = 0; ks < 2; ++ks) {
        q1f[ks] = *reinterpret_cast<const bf16x8*>(Q1 + (size_t)(q0 + w*16 + lo)*ND + ks*32 + hi8);
        q2f[ks] = *reinterpret_cast<const bf16x8*>(Q2 + (size_t)(q0 + w*16 + lo)*ND + ks*32 + hi8);
    }

    f32x4 yacc[4] = {};

    const int srow = w * 8 + (lane >> 3);
    const int scol = (lane & 7) * 8;
    const int rot  = (tid >> 3) & 7;      // rotation to break Vt write bank conflicts

    const int nkt = qt + 1;
    for (int kt = 0; kt < nkt; ++kt) {
        const int k0 = kt * 64;
        // --- stage K1, K2 (linear LDS via global_load_lds) ---
        #pragma unroll
        for (int i = 0; i < 2; ++i) {
            const unsigned loff = (unsigned)(i * 4096 + w * 1024);
            __builtin_amdgcn_global_load_lds(
                AS1C(K1 + (size_t)(k0 + i*32 + srow) * ND + scol),
                AS3((char*)K1s + loff), 16, 0, 0);
            __builtin_amdgcn_global_load_lds(
                AS1C(K2 + (size_t)(k0 + i*32 + srow) * ND + scol),
                AS3((char*)K2s + loff), 16, 0, 0);
        }
        // --- stage V transposed (reg -> LDS) ---
        #pragma unroll
        for (int i = 0; i < 2; ++i) {
            const int t  = i*32 + (tid >> 3);
            const int d0 = (tid & 7) * 8;
            bf16x8 vv = *reinterpret_cast<const bf16x8*>(V + (size_t)(k0 + t) * ND + d0);
            #pragma unroll
            for (int j = 0; j < 8; ++j) {
                const int jj = (j + rot) & 7;
                Vt[(d0 + jj)*72 + t] = vv[jj];
            }
        }
        __syncthreads();

        // --- S1 = Q1*K1^T, S2 = Q2*K2^T (16 q-rows x 64 k-cols per wave) ---
        f32x4 s1[4] = {}, s2[4] = {};
        #pragma unroll
        for (int ks = 0; ks < 2; ++ks)
            #pragma unroll
            for (int sub = 0; sub < 4; ++sub) {
                bf16x8 k1f = *reinterpret_cast<const bf16x8*>(&K1s[(sub*16 + lo)*64 + ks*32 + hi8]);
                bf16x8 k2f = *reinterpret_cast<const bf16x8*>(&K2s[(sub*16 + lo)*64 + ks*32 + hi8]);
                s1[sub] = __builtin_amdgcn_mfma_f32_16x16x32_bf16(q1f[ks], k1f, s1[sub], 0, 0, 0);
                s2[sub] = __builtin_amdgcn_mfma_f32_16x16x32_bf16(q2f[ks], k2f, s2[sub], 0, 0, 0);
            }

        // --- combine + causal mask -> P (bf16) via per-wave LDS ---
        #pragma unroll
        for (int sub = 0; sub < 4; ++sub)
            #pragma unroll
            for (int r = 0; r < 4; ++r) {
                const int qg = q0 + w*16 + hi*4 + r;
                const int kg = k0 + sub*16 + lo;
                float pv = (kg <= qg) ? s1[sub][r] * s2[sub][r] * (1.0f/4096.0f) : 0.0f;
                Pl[w][(hi*4 + r)*72 + sub*16 + lo] = (bf16)pv;
            }
        asm volatile("s_waitcnt lgkmcnt(0)" ::: "memory");
        __builtin_amdgcn_sched_barrier(0);

        // --- Y += P * V ---
        #pragma unroll
        for (int ks = 0; ks < 2; ++ks) {
            bf16x8 pf = *reinterpret_cast<const bf16x8*>(&Pl[w][lo*72 + ks*32 + hi8]);
            #pragma unroll
            for (int n = 0; n < 4; ++n) {
                bf16x8 vf = *reinterpret_cast<const bf16x8*>(&Vt[(n*16 + lo)*72 + ks*32 + hi8]);
                yacc[n] = __builtin_amdgcn_mfma_f32_16x16x32_bf16(pf, vf, yacc[n], 0, 0, 0);
            }
        }
        __syncthreads();   // protect K1s/K2s/Vt before next stage
    }

    // --- stage Y tile (16 rows x 64 cols, per wave) then coalesced 16B stores ---
    #pragma unroll
    for (int n = 0; n < 4; ++n)
        #pragma unroll
        for (int r = 0; r < 4; ++r)
            Pl[w][(hi*4 + r)*72 + n*16 + lo] = (bf16)yacc[n][r];
    __builtin_amdgcn_s_waitcnt(0);  // no-op placeholder; compiler orders LDS below

    #pragma unroll
    for (int pass = 0; pass < 2; ++pass) {
        const int idx = pass*64 + lane;      // 0..127
        const int row = idx >> 3;            // 0..15
        const int cc  = idx & 7;             // 16B chunk
        bf16x8 val = *reinterpret_cast<const bf16x8*>(&Pl[w][row*72 + cc*8]);
        const int t = q0 + w*16 + row;
        const int c = h*ND + cc*8;
        *reinterpret_cast<bf16x8*>(Y + ((size_t)b*NT + t)*NC + c) = val;
    }
}

// ---------------- launch ----------------
extern "C" void kernel_launch(void* const* d_in, const int* in_sizes, int n_in,
                              void* d_out, int out_size, void* d_ws, size_t ws_size,
                              hipStream_t stream)
{
    const float* x    = (const float*)d_in[0];
    const float* Wq1  = (const float*)d_in[1];
    const float* Wk1  = (const float*)d_in[2];
    const float* Wq2  = (const float*)d_in[3];
    const float* Wk2  = (const float*)d_in[4];
    const float* Wv   = (const float*)d_in[5];
    const float* Wout = (const float*)d_in[6];

    char* ws = (char*)d_ws;
    bf16*   Xbf   = (bf16*)ws;                                            // 8 MB
    bf16*   Wcat  = (bf16*)(ws + (size_t)NBT*NC*2);                       // 10 MB
    bf16*   Woutb = (bf16*)(ws + (size_t)NBT*NC*2 + (size_t)5*NC*NC*2);   // 2 MB
    bf16*   QKV   = (bf16*)(ws + (size_t)NBT*NC*2 + (size_t)6*NC*NC*2);   // 40 MB
    bf16*   Ybf   = (bf16*)((char*)QKV + (size_t)5*NBT*NC*2);             // 8 MB
    float2* tbl   = (float2*)((char*)Ybf + (size_t)NBT*NC*2);             // 512 KB

    cast_kernel<<<dim3(NBT*NC/1024), 256, 0, stream>>>(x, Xbf, NBT*NC);
    const float* Ws[5] = {Wq1, Wk1, Wq2, Wk2, Wv};
    for (int p = 0; p < 5; ++p)
        cast_kernel<<<dim3(NC*NC/1024), 256, 0, stream>>>(Ws[p], Wcat + (size_t)p*NC*NC, NC*NC);
    cast_kernel<<<dim3(NC*NC/1024), 256, 0, stream>>>(Wout, Woutb, NC*NC);
    rope_table_kernel<<<dim3(NT*32/256), 256, 0, stream>>>(tbl);

    // fused 5-projection GEMM, RoPE in epilogue -> QKV [p][b][h][t][d]
    gemm_bt<0><<<dim3(5*NC/128, NBT/128), 256, 0, stream>>>(Xbf, Wcat, (void*)QKV, NBT, 5*NC, NC, tbl);
    // fused bilinear attention -> Ybf [b][t][c]
    attn_kernel<<<dim3(NT/64, NH, NB), 256, 0, stream>>>(QKV, Ybf);
    // output projection -> fp32 d_out
    gemm_bt<1><<<dim3(NC/128, NBT/128), 256, 0, stream>>>(Ybf, Woutb, d_out, NBT, NC, NC, tbl);
}

// Round 3
// 232.973 us; speedup vs baseline: 3.1436x; 1.2922x over previous
//
#include <hip/hip_runtime.h>
#include <hip/hip_bf16.h>
#include <math.h>

typedef __bf16 bf16;
typedef __bf16 bf16x8 __attribute__((ext_vector_type(8)));
typedef float  f32x4  __attribute__((ext_vector_type(4)));

#define NB    2
#define NT    2048
#define NH    16
#define ND    64
#define NC    1024
#define NBT   4096   /* NB*NT */
#define NQT   32     /* NT/64 */

#define AS1C(p) ((const __attribute__((address_space(1))) void*)(p))
#define AS3(p)  ((__attribute__((address_space(3))) void*)(p))

#define MFMA(a,b,c) __builtin_amdgcn_mfma_f32_16x16x32_bf16(a, b, c, 0, 0, 0)

// ---------------- fp32 -> bf16 cast ----------------
__global__ void cast_kernel(const float* __restrict__ src, bf16* __restrict__ dst, int n)
{
    int i = (blockIdx.x * blockDim.x + threadIdx.x) * 4;
    if (i + 3 < n) {
        float4 v = *reinterpret_cast<const float4*>(src + i);
        dst[i+0] = (bf16)v.x;
        dst[i+1] = (bf16)v.y;
        dst[i+2] = (bf16)v.z;
        dst[i+3] = (bf16)v.w;
    }
}

// ---------------- rope cos/sin table (bf16-rounded, fp32 storage) ----------------
__global__ void rope_table_kernel(float2* __restrict__ tbl)
{
    int i = blockIdx.x * 256 + threadIdx.x;   // 0 .. NT*32-1
    int t = i >> 5, j = i & 31;
    float invf = 1.0f / powf(10000.0f, (float)j * (1.0f/32.0f));
    float fr = (float)t * invf;
    float2 cs;
    cs.x = (float)(bf16)cosf(fr);
    cs.y = (float)(bf16)sinf(fr);
    tbl[i] = cs;
}

// ---------------- GEMM  C = A(MxK) * B(NxK)^T ----------------
template<int EPI>
__global__ __launch_bounds__(256)
void gemm_bt(const bf16* __restrict__ A, const bf16* __restrict__ Bw,
             void* __restrict__ Cout, int M, int N, int K,
             const float2* __restrict__ tbl)
{
    __shared__ bf16 smem[128*128];          // 32 KB: As(16KB)+Bs(16KB), reused as C-tile
    bf16* As = smem;
    bf16* Bs = smem + 128*64;

    const int tid  = threadIdx.x;
    const int lane = tid & 63;
    const int w    = tid >> 6;       // wave 0..3
    const int wr   = w >> 1;         // 2x2 wave grid
    const int wc   = w & 1;
    const int row0 = blockIdx.y * 128;
    const int col0 = blockIdx.x * 128;

    const int lo   = lane & 15;
    const int hi8  = (lane >> 4) * 8;
    const int srow = w * 8 + (lane >> 3);  // staging row within a 32-row pass
    const int scol = (lane & 7) * 8;       // staging col (elements)

    f32x4 acc[4][4] = {};

    for (int kt = 0; kt < K; kt += 64) {
        #pragma unroll
        for (int i = 0; i < 4; ++i) {
            const unsigned loff = (unsigned)(i * 4096 + w * 1024); // + lane*16 by HW
            __builtin_amdgcn_global_load_lds(
                AS1C(A + (size_t)(row0 + i*32 + srow) * K + kt + scol),
                AS3((char*)As + loff), 16, 0, 0);
            __builtin_amdgcn_global_load_lds(
                AS1C(Bw + (size_t)(col0 + i*32 + srow) * K + kt + scol),
                AS3((char*)Bs + loff), 16, 0, 0);
        }
        __syncthreads();
        #pragma unroll
        for (int ks = 0; ks < 2; ++ks) {
            bf16x8 af[4], bfr[4];
            #pragma unroll
            for (int m = 0; m < 4; ++m)
                af[m] = *reinterpret_cast<const bf16x8*>(&As[(wr*64 + m*16 + lo)*64 + ks*32 + hi8]);
            #pragma unroll
            for (int n = 0; n < 4; ++n)
                bfr[n] = *reinterpret_cast<const bf16x8*>(&Bs[(wc*64 + n*16 + lo)*64 + ks*32 + hi8]);
            #pragma unroll
            for (int m = 0; m < 4; ++m)
                #pragma unroll
                for (int n = 0; n < 4; ++n)
                    acc[m][n] = MFMA(af[m], bfr[n], acc[m][n]);
        }
        __syncthreads();
    }

    const int rb = (lane >> 4) * 4;
    if constexpr (EPI == 1) {
        float* Cp = (float*)Cout;
        #pragma unroll
        for (int m = 0; m < 4; ++m)
            #pragma unroll
            for (int n = 0; n < 4; ++n)
                #pragma unroll
                for (int r = 0; r < 4; ++r) {
                    int row = row0 + wr*64 + m*16 + rb + r;
                    int col = col0 + wc*64 + n*16 + lo;
                    Cp[(size_t)row * N + col] = acc[m][n][r];
                }
    } else {
        // ---- stage C tile (bf16, rope applied) into LDS with XOR swizzle ----
        bf16* Ct = smem;
        const bool rope = (col0 >> 10) < 4;
        if (rope) {
            #pragma unroll
            for (int m = 0; m < 4; ++m)
                #pragma unroll
                for (int r = 0; r < 4; ++r) {
                    const int rl = wr*64 + m*16 + rb + r;
                    const int t  = (row0 + rl) & (NT-1);
                    const unsigned key = ((unsigned)(rl >> 2) & 3) << 5;
                    #pragma unroll
                    for (int n = 0; n < 2; ++n) {
                        const int j = n*16 + lo;
                        float2 cs = tbl[t*32 + j];
                        float a1 = acc[m][n][r];     // d = j
                        float a2 = acc[m][n+2][r];   // d = j+32
                        const int c1 = wc*64 + j;
                        const int c2 = c1 + 32;
                        Ct[((unsigned)rl*256 + (((unsigned)c1*2) ^ key)) >> 1] = (bf16)(a1*cs.x + a2*cs.y);
                        Ct[((unsigned)rl*256 + (((unsigned)c2*2) ^ key)) >> 1] = (bf16)(a2*cs.x - a1*cs.y);
                    }
                }
        } else {
            #pragma unroll
            for (int m = 0; m < 4; ++m)
                #pragma unroll
                for (int r = 0; r < 4; ++r) {
                    const int rl = wr*64 + m*16 + rb + r;
                    const unsigned key = ((unsigned)(rl >> 2) & 3) << 5;
                    #pragma unroll
                    for (int n = 0; n < 4; ++n) {
                        const int c = wc*64 + n*16 + lo;
                        Ct[((unsigned)rl*256 + (((unsigned)c*2) ^ key)) >> 1] = (bf16)acc[m][n][r];
                    }
                }
        }
        __syncthreads();

        // ---- coalesced writeout: 128 rows x 16 chunks of 16B ----
        bf16* qkv = (bf16*)Cout;
        const int p  = col0 >> 10;
        const int h0 = (col0 >> 6) & (NH-1);
        #pragma unroll
        for (int it = 0; it < 8; ++it) {
            const int chunk = it*256 + tid;       // 0..2047
            const int rl = chunk >> 4;            // local row
            const int cc = chunk & 15;            // 16B chunk in row
            const unsigned key = ((unsigned)(rl >> 2) & 3) << 5;
            bf16x8 val = *reinterpret_cast<const bf16x8*>(
                (const char*)Ct + ((unsigned)rl*256 + (((unsigned)cc*16) ^ key)));
            const int rowg = row0 + rl;
            const int b = rowg >> 11;
            const int t = rowg & (NT-1);
            const int hh = h0 + (cc >> 3);
            const int d  = (cc & 7) * 8;
            *reinterpret_cast<bf16x8*>(
                qkv + ((((size_t)p*NB + b)*NH + hh)*NT + t)*ND + d) = val;
        }
    }
}

// ---------------- fused bilinear attention ----------------
// grid (NQT/2, H, B), 256 threads = 4 waves.
// Block bx owns q-tiles qa=bx and qb=NQT-1-bx -> every block does exactly
// NQT+1 tile passes (perfect balance). K1/K2/V staging shared by both q-tiles.
// 2-phase double-buffered staging; all LDS tiles XOR-chunk-swizzled.
__global__ __launch_bounds__(256, 2)
void attn_kernel(const bf16* __restrict__ qkv, bf16* __restrict__ Y)
{
    __shared__ bf16 K1s[2][64*64];
    __shared__ bf16 K2s[2][64*64];
    __shared__ bf16 Vts[2][64*64];
    __shared__ bf16 Pa [4][16*64];
    __shared__ bf16 Pb [4][16*64];

    const int tid  = threadIdx.x;
    const int lane = tid & 63;
    const int w    = tid >> 6;
    const int h = blockIdx.y, b = blockIdx.z;
    const int qa = blockIdx.x;          // 0..15
    const int qb = NQT - 1 - qa;        // 31..16

    const size_t plane = (size_t)NB * NH * NT * ND;
    const size_t bh    = ((size_t)b * NH + h) * (size_t)NT * ND;
    const bf16* Q1 = qkv + 0*plane + bh;
    const bf16* K1 = qkv + 1*plane + bh;
    const bf16* Q2 = qkv + 2*plane + bh;
    const bf16* K2 = qkv + 3*plane + bh;
    const bf16* V  = qkv + 4*plane + bh;

    const int lo  = lane & 15;
    const int hi  = lane >> 4;
    const int hi8 = hi * 8;

    // Q fragments for both q-tiles (A-operand, row = lane%16), K-dim = D = 64
    bf16x8 q1fa[2], q2fa[2], q1fb[2], q2fb[2];
    #pragma unroll
    for (int ks = 0; ks < 2; ++ks) {
        const size_t ra = (size_t)(qa*64 + w*16 + lo) * ND + ks*32 + hi8;
        const size_t rb = (size_t)(qb*64 + w*16 + lo) * ND + ks*32 + hi8;
        q1fa[ks] = *reinterpret_cast<const bf16x8*>(Q1 + ra);
        q2fa[ks] = *reinterpret_cast<const bf16x8*>(Q2 + ra);
        q1fb[ks] = *reinterpret_cast<const bf16x8*>(Q1 + rb);
        q2fb[ks] = *reinterpret_cast<const bf16x8*>(Q2 + rb);
    }

    f32x4 yacca[4] = {}, yaccb[4] = {};

    const int srow = tid >> 3;                          // 0..31 (== w*8 + (lane>>3))
    const int ssw  = ((tid & 7) ^ (srow & 7)) * 8;      // pre-swizzled source col (elems)
    const int vd0  = (tid & 7) * 8;
    const int vrot = tid & 7;

    auto stageK = [&](int buf, int k0) {
        #pragma unroll
        for (int i = 0; i < 2; ++i) {
            const unsigned loff = (unsigned)(i * 4096 + w * 1024);
            __builtin_amdgcn_global_load_lds(
                AS1C(K1 + (size_t)(k0 + i*32 + srow) * ND + ssw),
                AS3((char*)K1s[buf] + loff), 16, 0, 0);
            __builtin_amdgcn_global_load_lds(
                AS1C(K2 + (size_t)(k0 + i*32 + srow) * ND + ssw),
                AS3((char*)K2s[buf] + loff), 16, 0, 0);
        }
    };
    auto loadV = [&](int k0, bf16x8* vr) {
        #pragma unroll
        for (int i = 0; i < 2; ++i)
            vr[i] = *reinterpret_cast<const bf16x8*>(V + (size_t)(k0 + i*32 + srow) * ND + vd0);
    };
    auto writeV = [&](int buf, const bf16x8* vr) {
        #pragma unroll
        for (int i = 0; i < 2; ++i) {
            const int t = i*32 + srow;           // 0..63
            #pragma unroll
            for (int j = 0; j < 8; ++j) {
                const int jj = (j + vrot) & 7;   // key on tid&7: spreads banks
                const int d  = vd0 + jj;         // d&7 == jj
                const unsigned byte = (unsigned)(d*128 + (((t>>3) ^ jj) * 16) + (t&7)*2);
                *(bf16*)((char*)Vts[buf] + byte) = vr[i][jj];
            }
        }
    };

    bf16x8 vreg[2];
    stageK(0, 0);
    loadV(0, vreg);
    writeV(0, vreg);
    asm volatile("s_waitcnt vmcnt(0)" ::: "memory");
    __syncthreads();

    for (int kt = 0; kt <= qb; ++kt) {
        const int  cur = kt & 1;
        const bool pre = (kt < qb);
        const bool doA = (kt <= qa);
        const int  k0  = kt * 64;

        if (pre) { stageK(cur^1, k0 + 64); loadV(k0 + 64, vreg); }

        // --- S1/S2 for both q-tiles; K fragments shared ---
        f32x4 s1a[4] = {}, s2a[4] = {}, s1b[4] = {}, s2b[4] = {};
        #pragma unroll
        for (int ks = 0; ks < 2; ++ks)
            #pragma unroll
            for (int sub = 0; sub < 4; ++sub) {
                const unsigned kb = (unsigned)((sub*16 + lo)*128 + (((ks*4 + hi) ^ (lo & 7)) * 16));
                bf16x8 k1f = *reinterpret_cast<const bf16x8*>((const char*)K1s[cur] + kb);
                bf16x8 k2f = *reinterpret_cast<const bf16x8*>((const char*)K2s[cur] + kb);
                s1b[sub] = MFMA(q1fb[ks], k1f, s1b[sub]);
                s2b[sub] = MFMA(q2fb[ks], k2f, s2b[sub]);
                if (doA) {
                    s1a[sub] = MFMA(q1fa[ks], k1f, s1a[sub]);
                    s2a[sub] = MFMA(q2fa[ks], k2f, s2a[sub]);
                }
            }

        // --- combine + causal mask -> P (bf16), swizzled per-wave staging ---
        #pragma unroll
        for (int sub = 0; sub < 4; ++sub)
            #pragma unroll
            for (int r = 0; r < 4; ++r) {
                const int row = hi*4 + r;
                const int col = sub*16 + lo;
                const unsigned byte = (unsigned)(row*128 + (((col>>3) ^ (row&7))*16) + (col&7)*2);
                const int kg = k0 + col;
                {
                    const int qg = qb*64 + w*16 + row;
                    float pv = (kg <= qg) ? s1b[sub][r]*s2b[sub][r]*(1.0f/4096.0f) : 0.0f;
                    *(bf16*)((char*)Pb[w] + byte) = (bf16)pv;
                }
                if (doA) {
                    const int qg = qa*64 + w*16 + row;
                    float pv = (kg <= qg) ? s1a[sub][r]*s2a[sub][r]*(1.0f/4096.0f) : 0.0f;
                    *(bf16*)((char*)Pa[w] + byte) = (bf16)pv;
                }
            }
        asm volatile("s_waitcnt lgkmcnt(0)" ::: "memory");
        __builtin_amdgcn_sched_barrier(0);

        // --- Y += P * V ---
        #pragma unroll
        for (int ks = 0; ks < 2; ++ks) {
            const unsigned pby = (unsigned)(lo*128 + (((ks*4 + hi) ^ (lo & 7)) * 16));
            bf16x8 pfb = *reinterpret_cast<const bf16x8*>((const char*)Pb[w] + pby);
            bf16x8 pfa = {};
            if (doA) pfa = *reinterpret_cast<const bf16x8*>((const char*)Pa[w] + pby);
            #pragma unroll
            for (int n = 0; n < 4; ++n) {
                const unsigned vby = (unsigned)((n*16 + lo)*128 + (((ks*4 + hi) ^ (lo & 7)) * 16));
                bf16x8 vf = *reinterpret_cast<const bf16x8*>((const char*)Vts[cur] + vby);
                yaccb[n] = MFMA(pfb, vf, yaccb[n]);
                if (doA) yacca[n] = MFMA(pfa, vf, yacca[n]);
            }
        }

        if (pre) writeV(cur^1, vreg);
        asm volatile("s_waitcnt vmcnt(0)" ::: "memory");
        __syncthreads();
    }

    // --- writeout via swizzled per-wave staging, 16B coalesced stores ---
    auto writeOut = [&](int q0, const f32x4* ya, bf16* Pbuf) {
        #pragma unroll
        for (int n = 0; n < 4; ++n)
            #pragma unroll
            for (int r = 0; r < 4; ++r) {
                const int row = hi*4 + r;
                const int col = n*16 + lo;
                const unsigned byte = (unsigned)(row*128 + (((col>>3) ^ (row&7))*16) + (col&7)*2);
                *(bf16*)((char*)Pbuf + byte) = (bf16)ya[n][r];
            }
        asm volatile("s_waitcnt lgkmcnt(0)" ::: "memory");
        __builtin_amdgcn_sched_barrier(0);
        #pragma unroll
        for (int pass = 0; pass < 2; ++pass) {
            const int idx = pass*64 + lane;      // 0..127
            const int row = idx >> 3;            // 0..15
            const int cc  = idx & 7;             // 16B chunk
            bf16x8 val = *reinterpret_cast<const bf16x8*>(
                (const char*)Pbuf + row*128 + ((cc ^ (row&7))*16));
            const int t = q0 + w*16 + row;
            const int c = h*ND + cc*8;
            *reinterpret_cast<bf16x8*>(Y + ((size_t)b*NT + t)*NC + c) = val;
        }
    };
    writeOut(qa*64, yacca, Pa[w]);
    writeOut(qb*64, yaccb, Pb[w]);
}

// ---------------- launch ----------------
extern "C" void kernel_launch(void* const* d_in, const int* in_sizes, int n_in,
                              void* d_out, int out_size, void* d_ws, size_t ws_size,
                              hipStream_t stream)
{
    const float* x    = (const float*)d_in[0];
    const float* Wq1  = (const float*)d_in[1];
    const float* Wk1  = (const float*)d_in[2];
    const float* Wq2  = (const float*)d_in[3];
    const float* Wk2  = (const float*)d_in[4];
    const float* Wv   = (const float*)d_in[5];
    const float* Wout = (const float*)d_in[6];

    char* ws = (char*)d_ws;
    bf16*   Xbf   = (bf16*)ws;                                            // 8 MB
    bf16*   Wcat  = (bf16*)(ws + (size_t)NBT*NC*2);                       // 10 MB
    bf16*   Woutb = (bf16*)(ws + (size_t)NBT*NC*2 + (size_t)5*NC*NC*2);   // 2 MB
    bf16*   QKV   = (bf16*)(ws + (size_t)NBT*NC*2 + (size_t)6*NC*NC*2);   // 40 MB
    bf16*   Ybf   = (bf16*)((char*)QKV + (size_t)5*NBT*NC*2);             // 8 MB
    float2* tbl   = (float2*)((char*)Ybf + (size_t)NBT*NC*2);             // 512 KB

    cast_kernel<<<dim3(NBT*NC/1024), 256, 0, stream>>>(x, Xbf, NBT*NC);
    const float* Ws[5] = {Wq1, Wk1, Wq2, Wk2, Wv};
    for (int p = 0; p < 5; ++p)
        cast_kernel<<<dim3(NC*NC/1024), 256, 0, stream>>>(Ws[p], Wcat + (size_t)p*NC*NC, NC*NC);
    cast_kernel<<<dim3(NC*NC/1024), 256, 0, stream>>>(Wout, Woutb, NC*NC);
    rope_table_kernel<<<dim3(NT*32/256), 256, 0, stream>>>(tbl);

    // fused 5-projection GEMM, RoPE in epilogue -> QKV [p][b][h][t][d]
    gemm_bt<0><<<dim3(5*NC/128, NBT/128), 256, 0, stream>>>(Xbf, Wcat, (void*)QKV, NBT, 5*NC, NC, tbl);
    // fused bilinear attention -> Ybf [b][t][c]
    attn_kernel<<<dim3(NQT/2, NH, NB), 256, 0, stream>>>(QKV, Ybf);
    // output projection -> fp32 d_out
    gemm_bt<1><<<dim3(NC/128, NBT/128), 256, 0, stream>>>(Ybf, Woutb, d_out, NBT, NC, NC, tbl);
}

// Round 5
// 191.160 us; speedup vs baseline: 3.8312x; 1.2187x over previous
//
#include <hip/hip_runtime.h>
#include <hip/hip_bf16.h>
#include <math.h>

typedef __bf16 bf16;
typedef __bf16 bf16x8 __attribute__((ext_vector_type(8)));
typedef float  f32x4  __attribute__((ext_vector_type(4)));

#define NB    2
#define NT    2048
#define NH    16
#define ND    64
#define NC    1024
#define NBT   4096   /* NB*NT */
#define NQT   32     /* NT/64 */

#define AS1C(p) ((const __attribute__((address_space(1))) void*)(p))
#define AS3(p)  ((__attribute__((address_space(3))) void*)(p))

#define MFMA(a,b,c) __builtin_amdgcn_mfma_f32_16x16x32_bf16(a, b, c, 0, 0, 0)

// ---------------- fp32 -> bf16 casts ----------------
__global__ void cast_kernel(const float* __restrict__ src, bf16* __restrict__ dst, int n)
{
    int i = (blockIdx.x * blockDim.x + threadIdx.x) * 4;
    if (i + 3 < n) {
        float4 v = *reinterpret_cast<const float4*>(src + i);
        dst[i+0] = (bf16)v.x;
        dst[i+1] = (bf16)v.y;
        dst[i+2] = (bf16)v.z;
        dst[i+3] = (bf16)v.w;
    }
}

struct WPtrs { const float* p[6]; };
__global__ void cast6_kernel(WPtrs w, bf16* __restrict__ dst)
{
    const int mat = blockIdx.x >> 10;                       // block-uniform
    const int off = ((blockIdx.x & 1023) * 256 + threadIdx.x) * 4;
    float4 v = *reinterpret_cast<const float4*>(w.p[mat] + off);
    bf16* d = dst + (size_t)mat * NC * NC + off;
    d[0] = (bf16)v.x; d[1] = (bf16)v.y; d[2] = (bf16)v.z; d[3] = (bf16)v.w;
}

// ---------------- rope cos/sin table (bf16-rounded, fp32 storage) ----------------
__global__ void rope_table_kernel(float2* __restrict__ tbl)
{
    int i = blockIdx.x * 256 + threadIdx.x;   // 0 .. NT*32-1
    int t = i >> 5, j = i & 31;
    float invf = 1.0f / powf(10000.0f, (float)j * (1.0f/32.0f));
    float fr = (float)t * invf;
    float2 cs;
    cs.x = (float)(bf16)cosf(fr);
    cs.y = (float)(bf16)sinf(fr);
    tbl[i] = cs;
}

// ---------------- GEMM  C = A(MxK) * B(NxK)^T ----------------
// EPI=0: proj epilogue -> bf16 QKV. Planes 0..3 (q1,k1,q2,k2): [p][b][h][t][d],
//        RoPE applied, Q planes pre-scaled by 1/64. Plane 4 (v): TRANSPOSED
//        [4][b][h][d][t] so attention consumes V without any transpose work.
// EPI=1: plain fp32 row-major output
template<int EPI>
__global__ __launch_bounds__(256)
void gemm_bt(const bf16* __restrict__ A, const bf16* __restrict__ Bw,
             void* __restrict__ Cout, int M, int N, int K,
             const float2* __restrict__ tbl)
{
    __shared__ bf16 smem[128*128];          // 32 KB: As(16KB)+Bs(16KB), reused as C-tile
    bf16* As = smem;
    bf16* Bs = smem + 128*64;

    const int tid  = threadIdx.x;
    const int lane = tid & 63;
    const int w    = tid >> 6;       // wave 0..3
    const int wr   = w >> 1;         // 2x2 wave grid
    const int wc   = w & 1;
    const int row0 = blockIdx.y * 128;
    const int col0 = blockIdx.x * 128;

    const int lo   = lane & 15;
    const int hi8  = (lane >> 4) * 8;
    const int srow = w * 8 + (lane >> 3);
    const int scol = (lane & 7) * 8;

    f32x4 acc[4][4] = {};

    for (int kt = 0; kt < K; kt += 64) {
        #pragma unroll
        for (int i = 0; i < 4; ++i) {
            const unsigned loff = (unsigned)(i * 4096 + w * 1024);
            __builtin_amdgcn_global_load_lds(
                AS1C(A + (size_t)(row0 + i*32 + srow) * K + kt + scol),
                AS3((char*)As + loff), 16, 0, 0);
            __builtin_amdgcn_global_load_lds(
                AS1C(Bw + (size_t)(col0 + i*32 + srow) * K + kt + scol),
                AS3((char*)Bs + loff), 16, 0, 0);
        }
        __syncthreads();
        #pragma unroll
        for (int ks = 0; ks < 2; ++ks) {
            bf16x8 af[4], bfr[4];
            #pragma unroll
            for (int m = 0; m < 4; ++m)
                af[m] = *reinterpret_cast<const bf16x8*>(&As[(wr*64 + m*16 + lo)*64 + ks*32 + hi8]);
            #pragma unroll
            for (int n = 0; n < 4; ++n)
                bfr[n] = *reinterpret_cast<const bf16x8*>(&Bs[(wc*64 + n*16 + lo)*64 + ks*32 + hi8]);
            #pragma unroll
            for (int m = 0; m < 4; ++m)
                #pragma unroll
                for (int n = 0; n < 4; ++n)
                    acc[m][n] = MFMA(af[m], bfr[n], acc[m][n]);
        }
        __syncthreads();
    }

    const int rb = (lane >> 4) * 4;
    if constexpr (EPI == 1) {
        float* Cp = (float*)Cout;
        #pragma unroll
        for (int m = 0; m < 4; ++m)
            #pragma unroll
            for (int n = 0; n < 4; ++n)
                #pragma unroll
                for (int r = 0; r < 4; ++r) {
                    int row = row0 + wr*64 + m*16 + rb + r;
                    int col = col0 + wc*64 + n*16 + lo;
                    Cp[(size_t)row * N + col] = acc[m][n][r];
                }
    } else {
        bf16* Ct = smem;
        bf16* qkv = (bf16*)Cout;
        const int p  = col0 >> 10;
        const int h0 = (col0 >> 6) & (NH-1);
        if (p < 4) {
            // ---- RoPE + prescale, staged [row][col] with row-keyed XOR swizzle ----
            // exact: *2^-6 commutes with bf16 rounding -> no /4096 in attention
            const float qsc = (p == 0 || p == 2) ? 0.015625f : 1.0f;
            #pragma unroll
            for (int m = 0; m < 4; ++m)
                #pragma unroll
                for (int r = 0; r < 4; ++r) {
                    const int rl = wr*64 + m*16 + rb + r;
                    const int t  = (row0 + rl) & (NT-1);
                    const unsigned key = ((unsigned)(rl >> 2) & 3) << 5;
                    #pragma unroll
                    for (int n = 0; n < 2; ++n) {
                        const int j = n*16 + lo;
                        float2 cs = tbl[t*32 + j];
                        float a1 = acc[m][n][r];
                        float a2 = acc[m][n+2][r];
                        const int c1 = wc*64 + j;
                        const int c2 = c1 + 32;
                        Ct[((unsigned)rl*256 + (((unsigned)c1*2) ^ key)) >> 1] = (bf16)((a1*cs.x + a2*cs.y) * qsc);
                        Ct[((unsigned)rl*256 + (((unsigned)c2*2) ^ key)) >> 1] = (bf16)((a2*cs.x - a1*cs.y) * qsc);
                    }
                }
            __syncthreads();
            // ---- coalesced writeout: [p][b][h][t][d] ----
            #pragma unroll
            for (int it = 0; it < 8; ++it) {
                const int chunk = it*256 + tid;       // 0..2047
                const int rl = chunk >> 4;
                const int cc = chunk & 15;
                const unsigned key = ((unsigned)(rl >> 2) & 3) << 5;
                bf16x8 val = *reinterpret_cast<const bf16x8*>(
                    (const char*)Ct + ((unsigned)rl*256 + (((unsigned)cc*16) ^ key)));
                const int rowg = row0 + rl;
                const int b = rowg >> 11;
                const int t = rowg & (NT-1);
                const int hh = h0 + (cc >> 3);
                const int d  = (cc & 7) * 8;
                *reinterpret_cast<bf16x8*>(
                    qkv + ((((size_t)p*NB + b)*NH + hh)*NT + t)*ND + d) = val;
            }
        } else {
            // ---- V: stage TRANSPOSED Ct[c][rl], col-keyed XOR swizzle ----
            // byte(c,rl) = c*256 + ((rl*2) ^ ((c&7)<<4)); key multiple of 16 so
            // the 16B writeout chunks stay contiguous.
            #pragma unroll
            for (int m = 0; m < 4; ++m)
                #pragma unroll
                for (int r = 0; r < 4; ++r) {
                    const int rl = wr*64 + m*16 + rb + r;
                    #pragma unroll
                    for (int n = 0; n < 4; ++n) {
                        const int c = wc*64 + n*16 + lo;
                        *(bf16*)((char*)Ct + (unsigned)(c*256 + ((rl*2) ^ ((c&7)<<4))))
                            = (bf16)acc[m][n][r];
                    }
                }
            __syncthreads();
            // ---- coalesced writeout: [4][b][h][d][t] ----
            const int b  = row0 >> 11;
            const int t0 = row0 & (NT-1);
            #pragma unroll
            for (int it = 0; it < 8; ++it) {
                const int chunk = it*256 + tid;       // 0..2047
                const int c   = chunk >> 4;           // d-col 0..127
                const int tcc = chunk & 15;           // t-chunk of 8
                bf16x8 val = *reinterpret_cast<const bf16x8*>(
                    (const char*)Ct + (unsigned)(c*256 + ((tcc*16) ^ ((c&7)<<4))));
                const int hh = h0 + (c >> 6);
                const int d  = c & 63;
                *reinterpret_cast<bf16x8*>(
                    qkv + (((size_t)4*NB + b)*NH + hh)*(size_t)NT*ND
                        + (size_t)d*NT + t0 + tcc*8) = val;
            }
        }
    }
}

// ---------------- fused bilinear attention ----------------
// grid (NQT/2, H, B). Block bx owns q-tiles qa=bx, qb=31-bx (33 passes, balanced).
// K1/K2 and V^T all DMA-staged with pre-swizzled global source; all MFMA
// fragments read as conflict-free swizzled ds_read_b128 (K-pattern, proven 0-conflict).
__global__ __launch_bounds__(256, 2)
void attn_kernel(const bf16* __restrict__ qkv, bf16* __restrict__ Y)
{
    __shared__ bf16 K1s[2*4096];
    __shared__ bf16 K2s[2*4096];
    __shared__ bf16 Vts[2*4096];   // staged from V^T: [buf][d 0..63][t-chunk swz][8]
    __shared__ bf16 Pa [4][1024];
    __shared__ bf16 Pb [4][1024];

    const int tid  = threadIdx.x;
    const int lane = tid & 63;
    const int w    = tid >> 6;
    const int h = blockIdx.y, b = blockIdx.z;
    const int qa = blockIdx.x;
    const int qb = NQT - 1 - qa;

    const size_t plane = (size_t)NB * NH * NT * ND;
    const size_t bh    = ((size_t)b * NH + h) * (size_t)NT * ND;
    const bf16* Q1 = qkv + 0*plane + bh;
    const bf16* K1 = qkv + 1*plane + bh;
    const bf16* Q2 = qkv + 2*plane + bh;
    const bf16* K2 = qkv + 3*plane + bh;
    const bf16* V  = qkv + 4*plane + bh;   // V^T slab: [d][t]

    const int lo  = lane & 15;
    const int hi  = lane >> 4;
    const int hi8 = hi * 8;

    // Q fragments (pre-scaled by 1/64 at projection)
    bf16x8 q1fa[2], q2fa[2], q1fb[2], q2fb[2];
    #pragma unroll
    for (int dd = 0; dd < 2; ++dd) {
        const size_t ra = (size_t)(qa*64 + w*16 + lo) * ND + dd*32 + hi8;
        const size_t rbq = (size_t)(qb*64 + w*16 + lo) * ND + dd*32 + hi8;
        q1fa[dd] = *reinterpret_cast<const bf16x8*>(Q1 + ra);
        q2fa[dd] = *reinterpret_cast<const bf16x8*>(Q2 + ra);
        q1fb[dd] = *reinterpret_cast<const bf16x8*>(Q1 + rbq);
        q2fb[dd] = *reinterpret_cast<const bf16x8*>(Q2 + rbq);
    }

    f32x4 yacca[4] = {}, yaccb[4] = {};

    const int srow = tid >> 3;                          // 0..31
    const int ssw  = ((tid & 7) ^ (srow & 7)) * 8;      // pre-swizzled source col

    auto stageK = [&](int buf, int k0) {
        #pragma unroll
        for (int i = 0; i < 2; ++i) {
            const unsigned loff = (unsigned)(buf*8192 + i*4096 + w*1024);
            __builtin_amdgcn_global_load_lds(
                AS1C(K1 + (size_t)(k0 + i*32 + srow) * ND + ssw),
                AS3((char*)K1s + loff), 16, 0, 0);
            __builtin_amdgcn_global_load_lds(
                AS1C(K2 + (size_t)(k0 + i*32 + srow) * ND + ssw),
                AS3((char*)K2s + loff), 16, 0, 0);
        }
    };
    // V^T tile: 64 d-rows x 64 t-cols; LDS row d = 128B, source t pre-swizzled
    auto stageVT = [&](int buf, int k0) {
        #pragma unroll
        for (int i = 0; i < 2; ++i) {
            const int inst = w*2 + i;                       // 0..7
            const int d    = inst*8 + (lane >> 3);          // 0..63
            const int sc   = ((lane & 7) ^ ((lane >> 3) & 7)) * 8;
            __builtin_amdgcn_global_load_lds(
                AS1C(V + (size_t)d * NT + k0 + sc),
                AS3((char*)Vts + (unsigned)(buf*8192 + inst*1024)), 16, 0, 0);
        }
    };

    stageK(0, 0);
    stageVT(0, 0);
    asm volatile("s_waitcnt vmcnt(0)" ::: "memory");
    __syncthreads();

    for (int kt = 0; kt <= qb; ++kt) {
        const int  cur = kt & 1;
        const bool pre = (kt < qb);
        const bool doA = (kt <= qa);
        const int  k0  = kt * 64;

        if (pre) { stageK(cur^1, k0 + 64); stageVT(cur^1, k0 + 64); }

        const bf16* K1b = K1s + cur*4096;
        const bf16* K2b = K2s + cur*4096;

        // --- S1/S2 (Q pre-scaled: S = (QK^T)/64) ---
        f32x4 s1a[4] = {}, s2a[4] = {}, s1b[4] = {}, s2b[4] = {};
        __builtin_amdgcn_s_setprio(1);
        #pragma unroll
        for (int dd = 0; dd < 2; ++dd)
            #pragma unroll
            for (int sub = 0; sub < 4; ++sub) {
                const unsigned kb = (unsigned)((sub*16 + lo)*128 + (((dd*4 + hi) ^ (lo & 7)) * 16));
                bf16x8 k1f = *reinterpret_cast<const bf16x8*>((const char*)K1b + kb);
                bf16x8 k2f = *reinterpret_cast<const bf16x8*>((const char*)K2b + kb);
                s1b[sub] = MFMA(q1fb[dd], k1f, s1b[sub]);
                s2b[sub] = MFMA(q2fb[dd], k2f, s2b[sub]);
                if (doA) {
                    s1a[sub] = MFMA(q1fa[dd], k1f, s1a[sub]);
                    s2a[sub] = MFMA(q2fa[dd], k2f, s2a[sub]);
                }
            }
        __builtin_amdgcn_s_setprio(0);

        // --- combine -> P (bf16), mask only on the diagonal pass ---
        #define COMBINE(S1, S2, PB, DIAG)                                              \
            _Pragma("unroll")                                                          \
            for (int sub = 0; sub < 4; ++sub)                                          \
                _Pragma("unroll")                                                      \
                for (int r = 0; r < 4; ++r) {                                          \
                    const int row = hi*4 + r;                                          \
                    const int col = sub*16 + lo;                                       \
                    const unsigned byte = (unsigned)(row*128 + (((col>>3) ^ (row&7))*16) + (col&7)*2); \
                    float pv = S1[sub][r] * S2[sub][r];                                \
                    if (DIAG && col > w*16 + row) pv = 0.0f;                           \
                    *(bf16*)((char*)PB + byte) = (bf16)pv;                             \
                }
        if (kt == qb) { COMBINE(s1b, s2b, Pb[w], true) } else { COMBINE(s1b, s2b, Pb[w], false) }
        if (doA) {
            if (kt == qa) { COMBINE(s1a, s2a, Pa[w], true) } else { COMBINE(s1a, s2a, Pa[w], false) }
        }
        #undef COMBINE

        asm volatile("s_waitcnt lgkmcnt(0)" ::: "memory");
        __builtin_amdgcn_sched_barrier(0);

        // --- Y += P * V (V fragments: swizzled b128 reads, K-pattern) ---
        __builtin_amdgcn_s_setprio(1);
        #pragma unroll
        for (int ks = 0; ks < 2; ++ks) {
            const unsigned pby = (unsigned)(lo*128 + (((ks*4 + hi) ^ (lo & 7)) * 16));
            bf16x8 pfb = *reinterpret_cast<const bf16x8*>((const char*)Pb[w] + pby);
            bf16x8 pfa = {};
            if (doA) pfa = *reinterpret_cast<const bf16x8*>((const char*)Pa[w] + pby);
            #pragma unroll
            for (int n = 0; n < 4; ++n) {
                const unsigned vby = (unsigned)(cur*8192 + (n*16 + lo)*128 + (((ks*4 + hi) ^ (lo & 7)) * 16));
                bf16x8 vf = *reinterpret_cast<const bf16x8*>((const char*)Vts + vby);
                yaccb[n] = MFMA(pfb, vf, yaccb[n]);
                if (doA) yacca[n] = MFMA(pfa, vf, yacca[n]);
            }
        }
        __builtin_amdgcn_s_setprio(0);

        asm volatile("s_waitcnt vmcnt(0)" ::: "memory");
        __syncthreads();
    }

    // --- writeout via swizzled per-wave staging, 16B coalesced stores ---
    auto writeOut = [&](int q0, const f32x4* ya, bf16* Pbuf) {
        #pragma unroll
        for (int n = 0; n < 4; ++n)
            #pragma unroll
            for (int r = 0; r < 4; ++r) {
                const int row = hi*4 + r;
                const int col = n*16 + lo;
                const unsigned byte = (unsigned)(row*128 + (((col>>3) ^ (row&7))*16) + (col&7)*2);
                *(bf16*)((char*)Pbuf + byte) = (bf16)ya[n][r];
            }
        asm volatile("s_waitcnt lgkmcnt(0)" ::: "memory");
        __builtin_amdgcn_sched_barrier(0);
        #pragma unroll
        for (int pass = 0; pass < 2; ++pass) {
            const int idx = pass*64 + lane;
            const int row = idx >> 3;
            const int cc  = idx & 7;
            bf16x8 val = *reinterpret_cast<const bf16x8*>(
                (const char*)Pbuf + row*128 + ((cc ^ (row&7))*16));
            const int t = q0 + w*16 + row;
            const int c = h*ND + cc*8;
            *reinterpret_cast<bf16x8*>(Y + ((size_t)b*NT + t)*NC + c) = val;
        }
    };
    writeOut(qa*64, yacca, Pa[w]);
    writeOut(qb*64, yaccb, Pb[w]);
}

// ---------------- launch ----------------
extern "C" void kernel_launch(void* const* d_in, const int* in_sizes, int n_in,
                              void* d_out, int out_size, void* d_ws, size_t ws_size,
                              hipStream_t stream)
{
    const float* x = (const float*)d_in[0];

    char* ws = (char*)d_ws;
    bf16*   Xbf   = (bf16*)ws;                                            // 8 MB
    bf16*   Wcat  = (bf16*)(ws + (size_t)NBT*NC*2);                       // 12 MB (6 mats)
    bf16*   QKV   = (bf16*)(ws + (size_t)NBT*NC*2 + (size_t)6*NC*NC*2);   // 40 MB
    bf16*   Ybf   = (bf16*)((char*)QKV + (size_t)5*NBT*NC*2);             // 8 MB
    float2* tbl   = (float2*)((char*)Ybf + (size_t)NBT*NC*2);             // 512 KB
    bf16*   Woutb = Wcat + (size_t)5*NC*NC;

    cast_kernel<<<dim3(NBT*NC/1024), 256, 0, stream>>>(x, Xbf, NBT*NC);
    WPtrs wp;
    wp.p[0] = (const float*)d_in[1]; wp.p[1] = (const float*)d_in[2];
    wp.p[2] = (const float*)d_in[3]; wp.p[3] = (const float*)d_in[4];
    wp.p[4] = (const float*)d_in[5]; wp.p[5] = (const float*)d_in[6];
    cast6_kernel<<<dim3(6*1024), 256, 0, stream>>>(wp, Wcat);
    rope_table_kernel<<<dim3(NT*32/256), 256, 0, stream>>>(tbl);

    // fused 5-projection GEMM, RoPE+prescale in epilogue; V written transposed
    gemm_bt<0><<<dim3(5*NC/128, NBT/128), 256, 0, stream>>>(Xbf, Wcat, (void*)QKV, NBT, 5*NC, NC, tbl);
    // fused bilinear attention -> Ybf [b][t][c]
    attn_kernel<<<dim3(NQT/2, NH, NB), 256, 0, stream>>>(QKV, Ybf);
    // output projection -> fp32 d_out
    gemm_bt<1><<<dim3(NC/128, NBT/128), 256, 0, stream>>>(Ybf, Woutb, d_out, NBT, NC, NC, tbl);
}

// Round 6
// 179.791 us; speedup vs baseline: 4.0735x; 1.0632x over previous
//
#include <hip/hip_runtime.h>
#include <hip/hip_bf16.h>
#include <math.h>

typedef __bf16 bf16;
typedef __bf16 bf16x8 __attribute__((ext_vector_type(8)));
typedef float  f32x4  __attribute__((ext_vector_type(4)));

#define NB    2
#define NT    2048
#define NH    16
#define ND    64
#define NC    1024
#define NBT   4096   /* NB*NT */
#define NQT   32     /* NT/64 */

#define AS1C(p) ((const __attribute__((address_space(1))) void*)(p))
#define AS3(p)  ((__attribute__((address_space(3))) void*)(p))

#define MFMA(a,b,c) __builtin_amdgcn_mfma_f32_16x16x32_bf16(a, b, c, 0, 0, 0)

// ---------------- fp32 -> bf16 casts ----------------
__global__ void cast_kernel(const float* __restrict__ src, bf16* __restrict__ dst, int n)
{
    int i = (blockIdx.x * blockDim.x + threadIdx.x) * 4;
    if (i + 3 < n) {
        float4 v = *reinterpret_cast<const float4*>(src + i);
        dst[i+0] = (bf16)v.x;
        dst[i+1] = (bf16)v.y;
        dst[i+2] = (bf16)v.z;
        dst[i+3] = (bf16)v.w;
    }
}

struct WPtrs { const float* p[6]; };
__global__ void cast6_kernel(WPtrs w, bf16* __restrict__ dst)
{
    const int mat = blockIdx.x >> 10;                       // block-uniform
    const int off = ((blockIdx.x & 1023) * 256 + threadIdx.x) * 4;
    float4 v = *reinterpret_cast<const float4*>(w.p[mat] + off);
    bf16* d = dst + (size_t)mat * NC * NC + off;
    d[0] = (bf16)v.x; d[1] = (bf16)v.y; d[2] = (bf16)v.z; d[3] = (bf16)v.w;
}

// ---------------- rope cos/sin table (bf16-rounded, fp32 storage) ----------------
__global__ void rope_table_kernel(float2* __restrict__ tbl)
{
    int i = blockIdx.x * 256 + threadIdx.x;   // 0 .. NT*32-1
    int t = i >> 5, j = i & 31;
    float invf = 1.0f / powf(10000.0f, (float)j * (1.0f/32.0f));
    float fr = (float)t * invf;
    float2 cs;
    cs.x = (float)(bf16)cosf(fr);
    cs.y = (float)(bf16)sinf(fr);
    tbl[i] = cs;
}

// ---------------- projection GEMM: 256^2 tile, 512 thr, dbuf, swizzled ----------------
// C = Xbf(4096x1024) * Wcat(5120x1024)^T -> QKV planes with RoPE/prescale/V^T epilogue.
__global__ __launch_bounds__(512, 1)
void gemm_proj(const bf16* __restrict__ A, const bf16* __restrict__ Bw,
               bf16* __restrict__ qkv, const float2* __restrict__ tbl)
{
    __shared__ bf16 smem[2*32768];     // 128 KB: [buf][ A 256x64 | B 256x64 ]

    const int tid  = threadIdx.x;
    const int lane = tid & 63;
    const int w    = tid >> 6;          // 0..7
    const int wr   = w >> 2;            // 0..1  (128-row half)
    const int wc   = w & 3;             // 0..3  (64-col quarter)

    // XCD-aware bijective swizzle (320 blocks, 320%8==0)
    const int id  = blockIdx.x;
    const int swz = (id & 7) * 40 + (id >> 3);
    const int by  = swz / 20, bx = swz % 20;
    const int row0 = by * 256, col0 = bx * 256;

    const int lo  = lane & 15;
    const int hi  = lane >> 4;

    const int srow = tid >> 3;                      // 0..63 staging row in a 64-row pass
    const int ssw  = ((tid & 7) ^ (srow & 7)) * 8;  // pre-swizzled source col (elements)

    f32x4 acc[8][4] = {};

    auto stage = [&](int buf, int kt) {
        char* As = (char*)smem + buf*65536;
        char* Bs = As + 32768;
        #pragma unroll
        for (int i = 0; i < 4; ++i) {
            const unsigned loff = (unsigned)(i*8192 + w*1024);
            __builtin_amdgcn_global_load_lds(
                AS1C(A + (size_t)(row0 + i*64 + srow) * NC + kt + ssw),
                AS3(As + loff), 16, 0, 0);
            __builtin_amdgcn_global_load_lds(
                AS1C(Bw + (size_t)(col0 + i*64 + srow) * NC + kt + ssw),
                AS3(Bs + loff), 16, 0, 0);
        }
    };

    stage(0, 0);
    asm volatile("s_waitcnt vmcnt(0)" ::: "memory");
    __syncthreads();

    for (int kt = 0; kt < 16; ++kt) {
        const int cur = kt & 1;
        if (kt < 15) stage(cur ^ 1, (kt + 1) * 64);

        const char* As = (const char*)smem + cur*65536;
        const char* Bs = As + 32768;

        __builtin_amdgcn_s_setprio(1);
        #pragma unroll
        for (int ks = 0; ks < 2; ++ks) {
            bf16x8 af[8], bfr[4];
            #pragma unroll
            for (int m = 0; m < 8; ++m) {
                const int ar = wr*128 + m*16 + lo;
                af[m] = *reinterpret_cast<const bf16x8*>(
                    As + ar*128 + (((ks*4 + hi) ^ (lo & 7)) * 16));
            }
            #pragma unroll
            for (int n = 0; n < 4; ++n) {
                const int br = wc*64 + n*16 + lo;
                bfr[n] = *reinterpret_cast<const bf16x8*>(
                    Bs + br*128 + (((ks*4 + hi) ^ (lo & 7)) * 16));
            }
            #pragma unroll
            for (int m = 0; m < 8; ++m)
                #pragma unroll
                for (int n = 0; n < 4; ++n)
                    acc[m][n] = MFMA(af[m], bfr[n], acc[m][n]);
        }
        __builtin_amdgcn_s_setprio(0);

        asm volatile("s_waitcnt vmcnt(0)" ::: "memory");
        __syncthreads();
    }

    // ---------------- epilogue: C tile (256x256) via 128 KB LDS ----------------
    bf16* Ct = smem;
    const int p  = col0 >> 10;                 // plane (block-uniform; 256 | 1024)
    const int h0 = (col0 >> 6) & (NH-1);
    const int rb = hi * 4;

    if (p < 4) {
        // RoPE + prescale (Q planes x 2^-6, exact), staged [rl][c], row-keyed swizzle
        const float qsc = (p == 0 || p == 2) ? 0.015625f : 1.0f;
        #pragma unroll
        for (int m = 0; m < 8; ++m)
            #pragma unroll
            for (int r = 0; r < 4; ++r) {
                const int rl = wr*128 + m*16 + rb + r;
                const int t  = (row0 + rl) & (NT-1);
                const unsigned key = ((unsigned)(rl >> 2) & 3) << 5;
                #pragma unroll
                for (int n = 0; n < 2; ++n) {
                    const int j = n*16 + lo;
                    float2 cs = tbl[t*32 + j];
                    float a1 = acc[m][n][r];
                    float a2 = acc[m][n+2][r];
                    const int c1 = wc*64 + j;
                    const int c2 = c1 + 32;
                    *(bf16*)((char*)Ct + (unsigned)(rl*512 + (((unsigned)c1*2) ^ key)))
                        = (bf16)((a1*cs.x + a2*cs.y) * qsc);
                    *(bf16*)((char*)Ct + (unsigned)(rl*512 + (((unsigned)c2*2) ^ key)))
                        = (bf16)((a2*cs.x - a1*cs.y) * qsc);
                }
            }
        __syncthreads();
        // coalesced writeout: [p][b][h][t][d]
        #pragma unroll
        for (int it = 0; it < 16; ++it) {
            const int chunk = it*512 + tid;        // 0..8191
            const int rl = chunk >> 5;
            const int cc = chunk & 31;
            const unsigned key = ((unsigned)(rl >> 2) & 3) << 5;
            bf16x8 val = *reinterpret_cast<const bf16x8*>(
                (const char*)Ct + (unsigned)(rl*512 + (((unsigned)cc*16) ^ key)));
            const int rowg = row0 + rl;
            const int b = rowg >> 11;
            const int t = rowg & (NT-1);
            const int hh = h0 + (cc >> 3);
            const int d  = (cc & 7) * 8;
            *reinterpret_cast<bf16x8*>(
                qkv + ((((size_t)p*NB + b)*NH + hh)*NT + t)*ND + d) = val;
        }
    } else {
        // V: stage TRANSPOSED Ct[c][rl], col-keyed swizzle
        #pragma unroll
        for (int m = 0; m < 8; ++m)
            #pragma unroll
            for (int r = 0; r < 4; ++r) {
                const int rl = wr*128 + m*16 + rb + r;
                #pragma unroll
                for (int n = 0; n < 4; ++n) {
                    const int c = wc*64 + n*16 + lo;
                    *(bf16*)((char*)Ct + (unsigned)(c*512 + (((unsigned)rl*2) ^ ((c&7)<<4))))
                        = (bf16)acc[m][n][r];
                }
            }
        __syncthreads();
        // coalesced writeout: [4][b][h][d][t]
        const int b  = row0 >> 11;
        const int t0 = row0 & (NT-1);
        #pragma unroll
        for (int it = 0; it < 16; ++it) {
            const int chunk = it*512 + tid;        // 0..8191
            const int c   = chunk >> 5;            // 0..255 (d-col across 4 heads)
            const int tcc = chunk & 31;
            bf16x8 val = *reinterpret_cast<const bf16x8*>(
                (const char*)Ct + (unsigned)(c*512 + (((unsigned)tcc*16) ^ ((c&7)<<4))));
            const int hh = h0 + (c >> 6);
            const int d  = c & 63;
            *reinterpret_cast<bf16x8*>(
                qkv + (((size_t)4*NB + b)*NH + hh)*(size_t)NT*ND
                    + (size_t)d*NT + t0 + tcc*8) = val;
        }
    }
}

// ---------------- output GEMM  C = A(MxK) * B(NxK)^T, fp32 out (unchanged) ----------------
__global__ __launch_bounds__(256)
void gemm_out(const bf16* __restrict__ A, const bf16* __restrict__ Bw,
              float* __restrict__ Cp, int M, int N, int K)
{
    __shared__ bf16 smem[128*128];
    bf16* As = smem;
    bf16* Bs = smem + 128*64;

    const int tid  = threadIdx.x;
    const int lane = tid & 63;
    const int w    = tid >> 6;
    const int wr   = w >> 1;
    const int wc   = w & 1;
    const int row0 = blockIdx.y * 128;
    const int col0 = blockIdx.x * 128;

    const int lo   = lane & 15;
    const int hi8  = (lane >> 4) * 8;
    const int srow = w * 8 + (lane >> 3);
    const int scol = (lane & 7) * 8;

    f32x4 acc[4][4] = {};

    for (int kt = 0; kt < K; kt += 64) {
        #pragma unroll
        for (int i = 0; i < 4; ++i) {
            const unsigned loff = (unsigned)(i * 4096 + w * 1024);
            __builtin_amdgcn_global_load_lds(
                AS1C(A + (size_t)(row0 + i*32 + srow) * K + kt + scol),
                AS3((char*)As + loff), 16, 0, 0);
            __builtin_amdgcn_global_load_lds(
                AS1C(Bw + (size_t)(col0 + i*32 + srow) * K + kt + scol),
                AS3((char*)Bs + loff), 16, 0, 0);
        }
        __syncthreads();
        #pragma unroll
        for (int ks = 0; ks < 2; ++ks) {
            bf16x8 af[4], bfr[4];
            #pragma unroll
            for (int m = 0; m < 4; ++m)
                af[m] = *reinterpret_cast<const bf16x8*>(&As[(wr*64 + m*16 + lo)*64 + ks*32 + hi8]);
            #pragma unroll
            for (int n = 0; n < 4; ++n)
                bfr[n] = *reinterpret_cast<const bf16x8*>(&Bs[(wc*64 + n*16 + lo)*64 + ks*32 + hi8]);
            #pragma unroll
            for (int m = 0; m < 4; ++m)
                #pragma unroll
                for (int n = 0; n < 4; ++n)
                    acc[m][n] = MFMA(af[m], bfr[n], acc[m][n]);
        }
        __syncthreads();
    }

    const int rb = (lane >> 4) * 4;
    #pragma unroll
    for (int m = 0; m < 4; ++m)
        #pragma unroll
        for (int n = 0; n < 4; ++n)
            #pragma unroll
            for (int r = 0; r < 4; ++r) {
                int row = row0 + wr*64 + m*16 + rb + r;
                int col = col0 + wc*64 + n*16 + lo;
                Cp[(size_t)row * N + col] = acc[m][n][r];
            }
}

// ---------------- fused bilinear attention (unchanged from round 5) ----------------
__global__ __launch_bounds__(256, 2)
void attn_kernel(const bf16* __restrict__ qkv, bf16* __restrict__ Y)
{
    __shared__ bf16 K1s[2*4096];
    __shared__ bf16 K2s[2*4096];
    __shared__ bf16 Vts[2*4096];
    __shared__ bf16 Pa [4][1024];
    __shared__ bf16 Pb [4][1024];

    const int tid  = threadIdx.x;
    const int lane = tid & 63;
    const int w    = tid >> 6;
    const int h = blockIdx.y, b = blockIdx.z;
    const int qa = blockIdx.x;
    const int qb = NQT - 1 - qa;

    const size_t plane = (size_t)NB * NH * NT * ND;
    const size_t bh    = ((size_t)b * NH + h) * (size_t)NT * ND;
    const bf16* Q1 = qkv + 0*plane + bh;
    const bf16* K1 = qkv + 1*plane + bh;
    const bf16* Q2 = qkv + 2*plane + bh;
    const bf16* K2 = qkv + 3*plane + bh;
    const bf16* V  = qkv + 4*plane + bh;   // V^T slab: [d][t]

    const int lo  = lane & 15;
    const int hi  = lane >> 4;
    const int hi8 = hi * 8;

    bf16x8 q1fa[2], q2fa[2], q1fb[2], q2fb[2];
    #pragma unroll
    for (int dd = 0; dd < 2; ++dd) {
        const size_t ra  = (size_t)(qa*64 + w*16 + lo) * ND + dd*32 + hi8;
        const size_t rbq = (size_t)(qb*64 + w*16 + lo) * ND + dd*32 + hi8;
        q1fa[dd] = *reinterpret_cast<const bf16x8*>(Q1 + ra);
        q2fa[dd] = *reinterpret_cast<const bf16x8*>(Q2 + ra);
        q1fb[dd] = *reinterpret_cast<const bf16x8*>(Q1 + rbq);
        q2fb[dd] = *reinterpret_cast<const bf16x8*>(Q2 + rbq);
    }

    f32x4 yacca[4] = {}, yaccb[4] = {};

    const int srow = tid >> 3;
    const int ssw  = ((tid & 7) ^ (srow & 7)) * 8;

    auto stageK = [&](int buf, int k0) {
        #pragma unroll
        for (int i = 0; i < 2; ++i) {
            const unsigned loff = (unsigned)(buf*8192 + i*4096 + w*1024);
            __builtin_amdgcn_global_load_lds(
                AS1C(K1 + (size_t)(k0 + i*32 + srow) * ND + ssw),
                AS3((char*)K1s + loff), 16, 0, 0);
            __builtin_amdgcn_global_load_lds(
                AS1C(K2 + (size_t)(k0 + i*32 + srow) * ND + ssw),
                AS3((char*)K2s + loff), 16, 0, 0);
        }
    };
    auto stageVT = [&](int buf, int k0) {
        #pragma unroll
        for (int i = 0; i < 2; ++i) {
            const int inst = w*2 + i;
            const int d    = inst*8 + (lane >> 3);
            const int sc   = ((lane & 7) ^ ((lane >> 3) & 7)) * 8;
            __builtin_amdgcn_global_load_lds(
                AS1C(V + (size_t)d * NT + k0 + sc),
                AS3((char*)Vts + (unsigned)(buf*8192 + inst*1024)), 16, 0, 0);
        }
    };

    stageK(0, 0);
    stageVT(0, 0);
    asm volatile("s_waitcnt vmcnt(0)" ::: "memory");
    __syncthreads();

    for (int kt = 0; kt <= qb; ++kt) {
        const int  cur = kt & 1;
        const bool pre = (kt < qb);
        const bool doA = (kt <= qa);
        const int  k0  = kt * 64;

        if (pre) { stageK(cur^1, k0 + 64); stageVT(cur^1, k0 + 64); }

        const bf16* K1b = K1s + cur*4096;
        const bf16* K2b = K2s + cur*4096;

        f32x4 s1a[4] = {}, s2a[4] = {}, s1b[4] = {}, s2b[4] = {};
        __builtin_amdgcn_s_setprio(1);
        #pragma unroll
        for (int dd = 0; dd < 2; ++dd)
            #pragma unroll
            for (int sub = 0; sub < 4; ++sub) {
                const unsigned kb = (unsigned)((sub*16 + lo)*128 + (((dd*4 + hi) ^ (lo & 7)) * 16));
                bf16x8 k1f = *reinterpret_cast<const bf16x8*>((const char*)K1b + kb);
                bf16x8 k2f = *reinterpret_cast<const bf16x8*>((const char*)K2b + kb);
                s1b[sub] = MFMA(q1fb[dd], k1f, s1b[sub]);
                s2b[sub] = MFMA(q2fb[dd], k2f, s2b[sub]);
                if (doA) {
                    s1a[sub] = MFMA(q1fa[dd], k1f, s1a[sub]);
                    s2a[sub] = MFMA(q2fa[dd], k2f, s2a[sub]);
                }
            }
        __builtin_amdgcn_s_setprio(0);

        #define COMBINE(S1, S2, PB, DIAG)                                              \
            _Pragma("unroll")                                                          \
            for (int sub = 0; sub < 4; ++sub)                                          \
                _Pragma("unroll")                                                      \
                for (int r = 0; r < 4; ++r) {                                          \
                    const int row = hi*4 + r;                                          \
                    const int col = sub*16 + lo;                                       \
                    const unsigned byte = (unsigned)(row*128 + (((col>>3) ^ (row&7))*16) + (col&7)*2); \
                    float pv = S1[sub][r] * S2[sub][r];                                \
                    if (DIAG && col > w*16 + row) pv = 0.0f;                           \
                    *(bf16*)((char*)PB + byte) = (bf16)pv;                             \
                }
        if (kt == qb) { COMBINE(s1b, s2b, Pb[w], true) } else { COMBINE(s1b, s2b, Pb[w], false) }
        if (doA) {
            if (kt == qa) { COMBINE(s1a, s2a, Pa[w], true) } else { COMBINE(s1a, s2a, Pa[w], false) }
        }
        #undef COMBINE

        asm volatile("s_waitcnt lgkmcnt(0)" ::: "memory");
        __builtin_amdgcn_sched_barrier(0);

        __builtin_amdgcn_s_setprio(1);
        #pragma unroll
        for (int ks = 0; ks < 2; ++ks) {
            const unsigned pby = (unsigned)(lo*128 + (((ks*4 + hi) ^ (lo & 7)) * 16));
            bf16x8 pfb = *reinterpret_cast<const bf16x8*>((const char*)Pb[w] + pby);
            bf16x8 pfa = {};
            if (doA) pfa = *reinterpret_cast<const bf16x8*>((const char*)Pa[w] + pby);
            #pragma unroll
            for (int n = 0; n < 4; ++n) {
                const unsigned vby = (unsigned)(cur*8192 + (n*16 + lo)*128 + (((ks*4 + hi) ^ (lo & 7)) * 16));
                bf16x8 vf = *reinterpret_cast<const bf16x8*>((const char*)Vts + vby);
                yaccb[n] = MFMA(pfb, vf, yaccb[n]);
                if (doA) yacca[n] = MFMA(pfa, vf, yacca[n]);
            }
        }
        __builtin_amdgcn_s_setprio(0);

        asm volatile("s_waitcnt vmcnt(0)" ::: "memory");
        __syncthreads();
    }

    auto writeOut = [&](int q0, const f32x4* ya, bf16* Pbuf) {
        #pragma unroll
        for (int n = 0; n < 4; ++n)
            #pragma unroll
            for (int r = 0; r < 4; ++r) {
                const int row = hi*4 + r;
                const int col = n*16 + lo;
                const unsigned byte = (unsigned)(row*128 + (((col>>3) ^ (row&7))*16) + (col&7)*2);
                *(bf16*)((char*)Pbuf + byte) = (bf16)ya[n][r];
            }
        asm volatile("s_waitcnt lgkmcnt(0)" ::: "memory");
        __builtin_amdgcn_sched_barrier(0);
        #pragma unroll
        for (int pass = 0; pass < 2; ++pass) {
            const int idx = pass*64 + lane;
            const int row = idx >> 3;
            const int cc  = idx & 7;
            bf16x8 val = *reinterpret_cast<const bf16x8*>(
                (const char*)Pbuf + row*128 + ((cc ^ (row&7))*16));
            const int t = q0 + w*16 + row;
            const int c = h*ND + cc*8;
            *reinterpret_cast<bf16x8*>(Y + ((size_t)b*NT + t)*NC + c) = val;
        }
    };
    writeOut(qa*64, yacca, Pa[w]);
    writeOut(qb*64, yaccb, Pb[w]);
}

// ---------------- launch ----------------
extern "C" void kernel_launch(void* const* d_in, const int* in_sizes, int n_in,
                              void* d_out, int out_size, void* d_ws, size_t ws_size,
                              hipStream_t stream)
{
    const float* x = (const float*)d_in[0];

    char* ws = (char*)d_ws;
    bf16*   Xbf   = (bf16*)ws;                                            // 8 MB
    bf16*   Wcat  = (bf16*)(ws + (size_t)NBT*NC*2);                       // 12 MB (6 mats)
    bf16*   QKV   = (bf16*)(ws + (size_t)NBT*NC*2 + (size_t)6*NC*NC*2);   // 40 MB
    bf16*   Ybf   = (bf16*)((char*)QKV + (size_t)5*NBT*NC*2);             // 8 MB
    float2* tbl   = (float2*)((char*)Ybf + (size_t)NBT*NC*2);             // 512 KB
    bf16*   Woutb = Wcat + (size_t)5*NC*NC;

    cast_kernel<<<dim3(NBT*NC/1024), 256, 0, stream>>>(x, Xbf, NBT*NC);
    WPtrs wp;
    wp.p[0] = (const float*)d_in[1]; wp.p[1] = (const float*)d_in[2];
    wp.p[2] = (const float*)d_in[3]; wp.p[3] = (const float*)d_in[4];
    wp.p[4] = (const float*)d_in[5]; wp.p[5] = (const float*)d_in[6];
    cast6_kernel<<<dim3(6*1024), 256, 0, stream>>>(wp, Wcat);
    rope_table_kernel<<<dim3(NT*32/256), 256, 0, stream>>>(tbl);

    // fused 5-projection GEMM (256^2 tile), RoPE+prescale, V written transposed
    gemm_proj<<<dim3(320), 512, 0, stream>>>(Xbf, Wcat, QKV, tbl);
    // fused bilinear attention -> Ybf [b][t][c]
    attn_kernel<<<dim3(NQT/2, NH, NB), 256, 0, stream>>>(QKV, Ybf);
    // output projection -> fp32 d_out
    gemm_out<<<dim3(NC/128, NBT/128), 256, 0, stream>>>(Ybf, Woutb, (float*)d_out, NBT, NC, NC);
}

// Round 7
// 169.760 us; speedup vs baseline: 4.3142x; 1.0591x over previous
//
#include <hip/hip_runtime.h>
#include <hip/hip_bf16.h>
#include <math.h>

typedef __bf16 bf16;
typedef __bf16 bf16x8 __attribute__((ext_vector_type(8)));
typedef float  f32x4  __attribute__((ext_vector_type(4)));

#define NB    2
#define NT    2048
#define NH    16
#define ND    64
#define NC    1024
#define NBT   4096   /* NB*NT */
#define NQT   32     /* NT/64 */

#define AS1C(p) ((const __attribute__((address_space(1))) void*)(p))
#define AS3(p)  ((__attribute__((address_space(3))) void*)(p))

#define MFMA(a,b,c) __builtin_amdgcn_mfma_f32_16x16x32_bf16(a, b, c, 0, 0, 0)

// ---------------- fp32 -> bf16 casts ----------------
__global__ void cast_kernel(const float* __restrict__ src, bf16* __restrict__ dst, int n)
{
    int i = (blockIdx.x * blockDim.x + threadIdx.x) * 4;
    if (i + 3 < n) {
        float4 v = *reinterpret_cast<const float4*>(src + i);
        dst[i+0] = (bf16)v.x;
        dst[i+1] = (bf16)v.y;
        dst[i+2] = (bf16)v.z;
        dst[i+3] = (bf16)v.w;
    }
}

struct WPtrs { const float* p[6]; };
__global__ void cast6_kernel(WPtrs w, bf16* __restrict__ dst)
{
    const int mat = blockIdx.x >> 10;                       // block-uniform
    const int off = ((blockIdx.x & 1023) * 256 + threadIdx.x) * 4;
    float4 v = *reinterpret_cast<const float4*>(w.p[mat] + off);
    bf16* d = dst + (size_t)mat * NC * NC + off;
    d[0] = (bf16)v.x; d[1] = (bf16)v.y; d[2] = (bf16)v.z; d[3] = (bf16)v.w;
}

// ---------------- rope cos/sin table (bf16-rounded, fp32 storage) ----------------
__global__ void rope_table_kernel(float2* __restrict__ tbl)
{
    int i = blockIdx.x * 256 + threadIdx.x;   // 0 .. NT*32-1
    int t = i >> 5, j = i & 31;
    float invf = 1.0f / powf(10000.0f, (float)j * (1.0f/32.0f));
    float fr = (float)t * invf;
    float2 cs;
    cs.x = (float)(bf16)cosf(fr);
    cs.y = (float)(bf16)sinf(fr);
    tbl[i] = cs;
}

// ---------------- projection GEMM: 256^2 tile, 512 thr, dbuf, swizzled ----------------
// C = Xbf(4096x1024) * Wcat(5120x1024)^T -> QKV planes with RoPE/prescale/V^T epilogue.
__global__ __launch_bounds__(512, 1)
void gemm_proj(const bf16* __restrict__ A, const bf16* __restrict__ Bw,
               bf16* __restrict__ qkv, const float2* __restrict__ tbl)
{
    __shared__ bf16 smem[2*32768];     // 128 KB: [buf][ A 256x64 | B 256x64 ]

    const int tid  = threadIdx.x;
    const int lane = tid & 63;
    const int w    = tid >> 6;          // 0..7
    const int wr   = w >> 2;            // 0..1  (128-row half)
    const int wc   = w & 3;             // 0..3  (64-col quarter)

    // XCD-aware bijective swizzle (320 blocks, 320%8==0)
    const int id  = blockIdx.x;
    const int swz = (id & 7) * 40 + (id >> 3);
    const int by  = swz / 20, bx = swz % 20;
    const int row0 = by * 256, col0 = bx * 256;

    const int lo  = lane & 15;
    const int hi  = lane >> 4;

    const int srow = tid >> 3;                      // 0..63 staging row in a 64-row pass
    const int ssw  = ((tid & 7) ^ (srow & 7)) * 8;  // pre-swizzled source col (elements)

    f32x4 acc[8][4] = {};

    auto stage = [&](int buf, int kt) {
        char* As = (char*)smem + buf*65536;
        char* Bs = As + 32768;
        #pragma unroll
        for (int i = 0; i < 4; ++i) {
            const unsigned loff = (unsigned)(i*8192 + w*1024);
            __builtin_amdgcn_global_load_lds(
                AS1C(A + (size_t)(row0 + i*64 + srow) * NC + kt + ssw),
                AS3(As + loff), 16, 0, 0);
            __builtin_amdgcn_global_load_lds(
                AS1C(Bw + (size_t)(col0 + i*64 + srow) * NC + kt + ssw),
                AS3(Bs + loff), 16, 0, 0);
        }
    };

    stage(0, 0);
    asm volatile("s_waitcnt vmcnt(0)" ::: "memory");
    __syncthreads();

    for (int kt = 0; kt < 16; ++kt) {
        const int cur = kt & 1;
        if (kt < 15) stage(cur ^ 1, (kt + 1) * 64);

        const char* As = (const char*)smem + cur*65536;
        const char* Bs = As + 32768;

        __builtin_amdgcn_s_setprio(1);
        #pragma unroll
        for (int ks = 0; ks < 2; ++ks) {
            bf16x8 af[8], bfr[4];
            #pragma unroll
            for (int m = 0; m < 8; ++m) {
                const int ar = wr*128 + m*16 + lo;
                af[m] = *reinterpret_cast<const bf16x8*>(
                    As + ar*128 + (((ks*4 + hi) ^ (lo & 7)) * 16));
            }
            #pragma unroll
            for (int n = 0; n < 4; ++n) {
                const int br = wc*64 + n*16 + lo;
                bfr[n] = *reinterpret_cast<const bf16x8*>(
                    Bs + br*128 + (((ks*4 + hi) ^ (lo & 7)) * 16));
            }
            #pragma unroll
            for (int m = 0; m < 8; ++m)
                #pragma unroll
                for (int n = 0; n < 4; ++n)
                    acc[m][n] = MFMA(af[m], bfr[n], acc[m][n]);
        }
        __builtin_amdgcn_s_setprio(0);

        asm volatile("s_waitcnt vmcnt(0)" ::: "memory");
        __syncthreads();
    }

    // ---------------- epilogue: C tile (256x256) via 128 KB LDS ----------------
    bf16* Ct = smem;
    const int p  = col0 >> 10;                 // plane (block-uniform; 256 | 1024)
    const int h0 = (col0 >> 6) & (NH-1);
    const int rb = hi * 4;

    if (p < 4) {
        // RoPE + prescale (Q planes x 2^-6, exact), staged [rl][c], row-keyed swizzle
        const float qsc = (p == 0 || p == 2) ? 0.015625f : 1.0f;
        #pragma unroll
        for (int m = 0; m < 8; ++m)
            #pragma unroll
            for (int r = 0; r < 4; ++r) {
                const int rl = wr*128 + m*16 + rb + r;
                const int t  = (row0 + rl) & (NT-1);
                const unsigned key = ((unsigned)(rl >> 2) & 3) << 5;
                #pragma unroll
                for (int n = 0; n < 2; ++n) {
                    const int j = n*16 + lo;
                    float2 cs = tbl[t*32 + j];
                    float a1 = acc[m][n][r];
                    float a2 = acc[m][n+2][r];
                    const int c1 = wc*64 + j;
                    const int c2 = c1 + 32;
                    *(bf16*)((char*)Ct + (unsigned)(rl*512 + (((unsigned)c1*2) ^ key)))
                        = (bf16)((a1*cs.x + a2*cs.y) * qsc);
                    *(bf16*)((char*)Ct + (unsigned)(rl*512 + (((unsigned)c2*2) ^ key)))
                        = (bf16)((a2*cs.x - a1*cs.y) * qsc);
                }
            }
        __syncthreads();
        // coalesced writeout: [p][b][h][t][d]
        #pragma unroll
        for (int it = 0; it < 16; ++it) {
            const int chunk = it*512 + tid;        // 0..8191
            const int rl = chunk >> 5;
            const int cc = chunk & 31;
            const unsigned key = ((unsigned)(rl >> 2) & 3) << 5;
            bf16x8 val = *reinterpret_cast<const bf16x8*>(
                (const char*)Ct + (unsigned)(rl*512 + (((unsigned)cc*16) ^ key)));
            const int rowg = row0 + rl;
            const int b = rowg >> 11;
            const int t = rowg & (NT-1);
            const int hh = h0 + (cc >> 3);
            const int d  = (cc & 7) * 8;
            *reinterpret_cast<bf16x8*>(
                qkv + ((((size_t)p*NB + b)*NH + hh)*NT + t)*ND + d) = val;
        }
    } else {
        // V: stage TRANSPOSED Ct[c][rl], col-keyed swizzle
        #pragma unroll
        for (int m = 0; m < 8; ++m)
            #pragma unroll
            for (int r = 0; r < 4; ++r) {
                const int rl = wr*128 + m*16 + rb + r;
                #pragma unroll
                for (int n = 0; n < 4; ++n) {
                    const int c = wc*64 + n*16 + lo;
                    *(bf16*)((char*)Ct + (unsigned)(c*512 + (((unsigned)rl*2) ^ ((c&7)<<4))))
                        = (bf16)acc[m][n][r];
                }
            }
        __syncthreads();
        // coalesced writeout: [4][b][h][d][t]
        const int b  = row0 >> 11;
        const int t0 = row0 & (NT-1);
        #pragma unroll
        for (int it = 0; it < 16; ++it) {
            const int chunk = it*512 + tid;        // 0..8191
            const int c   = chunk >> 5;            // 0..255 (d-col across 4 heads)
            const int tcc = chunk & 31;
            bf16x8 val = *reinterpret_cast<const bf16x8*>(
                (const char*)Ct + (unsigned)(c*512 + (((unsigned)tcc*16) ^ ((c&7)<<4))));
            const int hh = h0 + (c >> 6);
            const int d  = c & 63;
            *reinterpret_cast<bf16x8*>(
                qkv + (((size_t)4*NB + b)*NH + hh)*(size_t)NT*ND
                    + (size_t)d*NT + t0 + tcc*8) = val;
        }
    }
}

// ---------------- output GEMM  C = A(MxK) * B(NxK)^T, fp32 out (unchanged) ----------------
__global__ __launch_bounds__(256)
void gemm_out(const bf16* __restrict__ A, const bf16* __restrict__ Bw,
              float* __restrict__ Cp, int M, int N, int K)
{
    __shared__ bf16 smem[128*128];
    bf16* As = smem;
    bf16* Bs = smem + 128*64;

    const int tid  = threadIdx.x;
    const int lane = tid & 63;
    const int w    = tid >> 6;
    const int wr   = w >> 1;
    const int wc   = w & 1;
    const int row0 = blockIdx.y * 128;
    const int col0 = blockIdx.x * 128;

    const int lo   = lane & 15;
    const int hi8  = (lane >> 4) * 8;
    const int srow = w * 8 + (lane >> 3);
    const int scol = (lane & 7) * 8;

    f32x4 acc[4][4] = {};

    for (int kt = 0; kt < K; kt += 64) {
        #pragma unroll
        for (int i = 0; i < 4; ++i) {
            const unsigned loff = (unsigned)(i * 4096 + w * 1024);
            __builtin_amdgcn_global_load_lds(
                AS1C(A + (size_t)(row0 + i*32 + srow) * K + kt + scol),
                AS3((char*)As + loff), 16, 0, 0);
            __builtin_amdgcn_global_load_lds(
                AS1C(Bw + (size_t)(col0 + i*32 + srow) * K + kt + scol),
                AS3((char*)Bs + loff), 16, 0, 0);
        }
        __syncthreads();
        #pragma unroll
        for (int ks = 0; ks < 2; ++ks) {
            bf16x8 af[4], bfr[4];
            #pragma unroll
            for (int m = 0; m < 4; ++m)
                af[m] = *reinterpret_cast<const bf16x8*>(&As[(wr*64 + m*16 + lo)*64 + ks*32 + hi8]);
            #pragma unroll
            for (int n = 0; n < 4; ++n)
                bfr[n] = *reinterpret_cast<const bf16x8*>(&Bs[(wc*64 + n*16 + lo)*64 + ks*32 + hi8]);
            #pragma unroll
            for (int m = 0; m < 4; ++m)
                #pragma unroll
                for (int n = 0; n < 4; ++n)
                    acc[m][n] = MFMA(af[m], bfr[n], acc[m][n]);
        }
        __syncthreads();
    }

    const int rb = (lane >> 4) * 4;
    #pragma unroll
    for (int m = 0; m < 4; ++m)
        #pragma unroll
        for (int n = 0; n < 4; ++n)
            #pragma unroll
            for (int r = 0; r < 4; ++r) {
                int row = row0 + wr*64 + m*16 + rb + r;
                int col = col0 + wc*64 + n*16 + lo;
                Cp[(size_t)row * N + col] = acc[m][n][r];
            }
}

// ---------------- fused bilinear attention ----------------
// 1-D grid of 512 blocks, decoded so that all 16 q-tile blocks of one (b,h)
// pair land on ONE XCD (xcd = lin&7 round-robin assumption): K1/K2/V planes
// are then fetched from HBM once per XCD and re-served from its private L2.
__global__ __launch_bounds__(256, 2)
void attn_kernel(const bf16* __restrict__ qkv, bf16* __restrict__ Y)
{
    __shared__ bf16 K1s[2*4096];
    __shared__ bf16 K2s[2*4096];
    __shared__ bf16 Vts[2*4096];
    __shared__ bf16 Pa [4][1024];
    __shared__ bf16 Pb [4][1024];

    const int tid  = threadIdx.x;
    const int lane = tid & 63;
    const int w    = tid >> 6;

    // XCD-locality decode: lin -> (xcd, slot); 4 (b,h) pairs per XCD, 16 blocks each
    const int lin  = blockIdx.x;           // 0..511
    const int xcd  = lin & 7;
    const int slot = lin >> 3;             // 0..63
    const int pair = xcd * 4 + (slot >> 4);   // 0..31
    const int qa   = slot & 15;
    const int h    = pair >> 1;
    const int b    = pair & 1;
    const int qb   = NQT - 1 - qa;

    const size_t plane = (size_t)NB * NH * NT * ND;
    const size_t bh    = ((size_t)b * NH + h) * (size_t)NT * ND;
    const bf16* Q1 = qkv + 0*plane + bh;
    const bf16* K1 = qkv + 1*plane + bh;
    const bf16* Q2 = qkv + 2*plane + bh;
    const bf16* K2 = qkv + 3*plane + bh;
    const bf16* V  = qkv + 4*plane + bh;   // V^T slab: [d][t]

    const int lo  = lane & 15;
    const int hi  = lane >> 4;
    const int hi8 = hi * 8;

    bf16x8 q1fa[2], q2fa[2], q1fb[2], q2fb[2];
    #pragma unroll
    for (int dd = 0; dd < 2; ++dd) {
        const size_t ra  = (size_t)(qa*64 + w*16 + lo) * ND + dd*32 + hi8;
        const size_t rbq = (size_t)(qb*64 + w*16 + lo) * ND + dd*32 + hi8;
        q1fa[dd] = *reinterpret_cast<const bf16x8*>(Q1 + ra);
        q2fa[dd] = *reinterpret_cast<const bf16x8*>(Q2 + ra);
        q1fb[dd] = *reinterpret_cast<const bf16x8*>(Q1 + rbq);
        q2fb[dd] = *reinterpret_cast<const bf16x8*>(Q2 + rbq);
    }

    f32x4 yacca[4] = {}, yaccb[4] = {};

    const int srow = tid >> 3;
    const int ssw  = ((tid & 7) ^ (srow & 7)) * 8;

    auto stageK = [&](int buf, int k0) {
        #pragma unroll
        for (int i = 0; i < 2; ++i) {
            const unsigned loff = (unsigned)(buf*8192 + i*4096 + w*1024);
            __builtin_amdgcn_global_load_lds(
                AS1C(K1 + (size_t)(k0 + i*32 + srow) * ND + ssw),
                AS3((char*)K1s + loff), 16, 0, 0);
            __builtin_amdgcn_global_load_lds(
                AS1C(K2 + (size_t)(k0 + i*32 + srow) * ND + ssw),
                AS3((char*)K2s + loff), 16, 0, 0);
        }
    };
    auto stageVT = [&](int buf, int k0) {
        #pragma unroll
        for (int i = 0; i < 2; ++i) {
            const int inst = w*2 + i;
            const int d    = inst*8 + (lane >> 3);
            const int sc   = ((lane & 7) ^ ((lane >> 3) & 7)) * 8;
            __builtin_amdgcn_global_load_lds(
                AS1C(V + (size_t)d * NT + k0 + sc),
                AS3((char*)Vts + (unsigned)(buf*8192 + inst*1024)), 16, 0, 0);
        }
    };

    stageK(0, 0);
    stageVT(0, 0);
    asm volatile("s_waitcnt vmcnt(0)" ::: "memory");
    __syncthreads();

    for (int kt = 0; kt <= qb; ++kt) {
        const int  cur = kt & 1;
        const bool pre = (kt < qb);
        const bool doA = (kt <= qa);
        const int  k0  = kt * 64;

        if (pre) { stageK(cur^1, k0 + 64); stageVT(cur^1, k0 + 64); }

        const bf16* K1b = K1s + cur*4096;
        const bf16* K2b = K2s + cur*4096;

        f32x4 s1a[4] = {}, s2a[4] = {}, s1b[4] = {}, s2b[4] = {};
        __builtin_amdgcn_s_setprio(1);
        #pragma unroll
        for (int dd = 0; dd < 2; ++dd)
            #pragma unroll
            for (int sub = 0; sub < 4; ++sub) {
                const unsigned kb = (unsigned)((sub*16 + lo)*128 + (((dd*4 + hi) ^ (lo & 7)) * 16));
                bf16x8 k1f = *reinterpret_cast<const bf16x8*>((const char*)K1b + kb);
                bf16x8 k2f = *reinterpret_cast<const bf16x8*>((const char*)K2b + kb);
                s1b[sub] = MFMA(q1fb[dd], k1f, s1b[sub]);
                s2b[sub] = MFMA(q2fb[dd], k2f, s2b[sub]);
                if (doA) {
                    s1a[sub] = MFMA(q1fa[dd], k1f, s1a[sub]);
                    s2a[sub] = MFMA(q2fa[dd], k2f, s2a[sub]);
                }
            }
        __builtin_amdgcn_s_setprio(0);

        #define COMBINE(S1, S2, PB, DIAG)                                              \
            _Pragma("unroll")                                                          \
            for (int sub = 0; sub < 4; ++sub)                                          \
                _Pragma("unroll")                                                      \
                for (int r = 0; r < 4; ++r) {                                          \
                    const int row = hi*4 + r;                                          \
                    const int col = sub*16 + lo;                                       \
                    const unsigned byte = (unsigned)(row*128 + (((col>>3) ^ (row&7))*16) + (col&7)*2); \
                    float pv = S1[sub][r] * S2[sub][r];                                \
                    if (DIAG && col > w*16 + row) pv = 0.0f;                           \
                    *(bf16*)((char*)PB + byte) = (bf16)pv;                             \
                }
        if (kt == qb) { COMBINE(s1b, s2b, Pb[w], true) } else { COMBINE(s1b, s2b, Pb[w], false) }
        if (doA) {
            if (kt == qa) { COMBINE(s1a, s2a, Pa[w], true) } else { COMBINE(s1a, s2a, Pa[w], false) }
        }
        #undef COMBINE

        asm volatile("s_waitcnt lgkmcnt(0)" ::: "memory");
        __builtin_amdgcn_sched_barrier(0);

        __builtin_amdgcn_s_setprio(1);
        #pragma unroll
        for (int ks = 0; ks < 2; ++ks) {
            const unsigned pby = (unsigned)(lo*128 + (((ks*4 + hi) ^ (lo & 7)) * 16));
            bf16x8 pfb = *reinterpret_cast<const bf16x8*>((const char*)Pb[w] + pby);
            bf16x8 pfa = {};
            if (doA) pfa = *reinterpret_cast<const bf16x8*>((const char*)Pa[w] + pby);
            #pragma unroll
            for (int n = 0; n < 4; ++n) {
                const unsigned vby = (unsigned)(cur*8192 + (n*16 + lo)*128 + (((ks*4 + hi) ^ (lo & 7)) * 16));
                bf16x8 vf = *reinterpret_cast<const bf16x8*>((const char*)Vts + vby);
                yaccb[n] = MFMA(pfb, vf, yaccb[n]);
                if (doA) yacca[n] = MFMA(pfa, vf, yacca[n]);
            }
        }
        __builtin_amdgcn_s_setprio(0);

        asm volatile("s_waitcnt vmcnt(0)" ::: "memory");
        __syncthreads();
    }

    auto writeOut = [&](int q0, const f32x4* ya, bf16* Pbuf) {
        #pragma unroll
        for (int n = 0; n < 4; ++n)
            #pragma unroll
            for (int r = 0; r < 4; ++r) {
                const int row = hi*4 + r;
                const int col = n*16 + lo;
                const unsigned byte = (unsigned)(row*128 + (((col>>3) ^ (row&7))*16) + (col&7)*2);
                *(bf16*)((char*)Pbuf + byte) = (bf16)ya[n][r];
            }
        asm volatile("s_waitcnt lgkmcnt(0)" ::: "memory");
        __builtin_amdgcn_sched_barrier(0);
        #pragma unroll
        for (int pass = 0; pass < 2; ++pass) {
            const int idx = pass*64 + lane;
            const int row = idx >> 3;
            const int cc  = idx & 7;
            bf16x8 val = *reinterpret_cast<const bf16x8*>(
                (const char*)Pbuf + row*128 + ((cc ^ (row&7))*16));
            const int t = q0 + w*16 + row;
            const int c = h*ND + cc*8;
            *reinterpret_cast<bf16x8*>(Y + ((size_t)b*NT + t)*NC + c) = val;
        }
    };
    writeOut(qa*64, yacca, Pa[w]);
    writeOut(qb*64, yaccb, Pb[w]);
}

// ---------------- launch ----------------
extern "C" void kernel_launch(void* const* d_in, const int* in_sizes, int n_in,
                              void* d_out, int out_size, void* d_ws, size_t ws_size,
                              hipStream_t stream)
{
    const float* x = (const float*)d_in[0];

    char* ws = (char*)d_ws;
    bf16*   Xbf   = (bf16*)ws;                                            // 8 MB
    bf16*   Wcat  = (bf16*)(ws + (size_t)NBT*NC*2);                       // 12 MB (6 mats)
    bf16*   QKV   = (bf16*)(ws + (size_t)NBT*NC*2 + (size_t)6*NC*NC*2);   // 40 MB
    bf16*   Ybf   = (bf16*)((char*)QKV + (size_t)5*NBT*NC*2);             // 8 MB
    float2* tbl   = (float2*)((char*)Ybf + (size_t)NBT*NC*2);             // 512 KB
    bf16*   Woutb = Wcat + (size_t)5*NC*NC;

    cast_kernel<<<dim3(NBT*NC/1024), 256, 0, stream>>>(x, Xbf, NBT*NC);
    WPtrs wp;
    wp.p[0] = (const float*)d_in[1]; wp.p[1] = (const float*)d_in[2];
    wp.p[2] = (const float*)d_in[3]; wp.p[3] = (const float*)d_in[4];
    wp.p[4] = (const float*)d_in[5]; wp.p[5] = (const float*)d_in[6];
    cast6_kernel<<<dim3(6*1024), 256, 0, stream>>>(wp, Wcat);
    rope_table_kernel<<<dim3(NT*32/256), 256, 0, stream>>>(tbl);

    // fused 5-projection GEMM (256^2 tile), RoPE+prescale, V written transposed
    gemm_proj<<<dim3(320), 512, 0, stream>>>(Xbf, Wcat, QKV, tbl);
    // fused bilinear attention -> Ybf [b][t][c]  (XCD-local 1-D grid)
    attn_kernel<<<dim3(512), 256, 0, stream>>>(QKV, Ybf);
    // output projection -> fp32 d_out
    gemm_out<<<dim3(NC/128, NBT/128), 256, 0, stream>>>(Ybf, Woutb, (float*)d_out, NBT, NC, NC);
}